// Round 2
// baseline (1370.973 us; speedup 1.0000x reference)
//
#include <hip/hip_runtime.h>
#include <hip/hip_bf16.h>
#include <math.h>

#define B_ 64
#define N_ 1024
#define E_ 524288
#define K1_ 512
#define K2_ 256
#define K3_ 128
#define M0_ 65536
#define M1_ 32768
#define M2_ 16384
#define M3_ 8192

static __device__ __forceinline__ float eluf(float x){ return x > 0.f ? x : expm1f(x); }

__global__ void k_fill(float* __restrict__ p, float v, int n){
  int i = blockIdx.x*256 + threadIdx.x; if (i<n) p[i]=v;
}

// Tiled GEMM: block computes 64 rows x BN cols. K tiled by 32. Fused self-loop
// epilogue: H = X@W; OUT = b + H * 2*dinv^2  (scatter then accumulates into OUT).
template<int BN>
__global__ __launch_bounds__(256) void k_mm(const float* __restrict__ X,
    const float* __restrict__ W, const float* __restrict__ bias,
    const float* __restrict__ dinv, float* __restrict__ H, float* __restrict__ OUT,
    int M, int K, int N){
  constexpr int TX = BN/4;      // threads across cols (each owns 4 cols)
  constexpr int TY = 256/TX;
  constexpr int RM = 64/TY;     // rows per thread
  __shared__ float Xs[64][36];  // pad 36: 16B-aligned rows, conflict-free col reads
  __shared__ float Ws[32][BN];
  const int t = threadIdx.x;
  const int tx = t % TX, ty = t / TX;
  const int m0 = blockIdx.x*64, n0 = blockIdx.y*BN;
  float acc[RM][4];
  #pragma unroll
  for (int r=0;r<RM;++r){acc[r][0]=0.f;acc[r][1]=0.f;acc[r][2]=0.f;acc[r][3]=0.f;}
  for (int k0=0;k0<K;k0+=32){
    #pragma unroll
    for (int r=0;r<2;++r){            // 512 float4s of X tile
      int fi=r*256+t, row=fi>>3, q=fi&7;
      *(float4*)(&Xs[row][q*4]) = *(const float4*)(X + (size_t)(m0+row)*K + k0 + q*4);
    }
    #pragma unroll
    for (int r=0;r<BN/32;++r){        // 8*BN float4s of W tile
      int fi=r*256+t, row=fi/(BN/4), q=fi%(BN/4);
      *(float4*)(&Ws[row][q*4]) = *(const float4*)(W + (size_t)(k0+row)*N + n0 + q*4);
    }
    __syncthreads();
    #pragma unroll
    for (int kk=0;kk<32;++kk){
      float4 wv = *(const float4*)(&Ws[kk][tx*4]);
      #pragma unroll
      for (int r=0;r<RM;++r){
        float xv = Xs[ty*RM+r][kk];
        acc[r][0]=fmaf(xv,wv.x,acc[r][0]);
        acc[r][1]=fmaf(xv,wv.y,acc[r][1]);
        acc[r][2]=fmaf(xv,wv.z,acc[r][2]);
        acc[r][3]=fmaf(xv,wv.w,acc[r][3]);
      }
    }
    __syncthreads();
  }
  #pragma unroll
  for (int r=0;r<RM;++r){
    int m = m0 + ty*RM + r;
    float di = dinv[m]; float sc = 2.f*di*di;
    int n = n0 + tx*4;
    float4 h; h.x=acc[r][0];h.y=acc[r][1];h.z=acc[r][2];h.w=acc[r][3];
    *(float4*)(H + (size_t)m*N + n) = h;
    float4 o; o.x=fmaf(h.x,sc,bias[n]); o.y=fmaf(h.y,sc,bias[n+1]);
    o.z=fmaf(h.z,sc,bias[n+2]); o.w=fmaf(h.w,sc,bias[n+3]);
    *(float4*)(OUT + (size_t)m*N + n) = o;
  }
}

// degree histogram over full level-0 edge list (weights all 1)
__global__ void k_deg_full(const int* __restrict__ dst, float* __restrict__ deg){
  int i = blockIdx.x*256 + threadIdx.x; if (i>=E_) return;
  atomicAdd(&deg[dst[i]], 1.f);
}

// degree over compacted list (count-driven grid-stride)
__global__ void k_deg_cmp(const int* __restrict__ dstC, const int* __restrict__ cnt,
                          float* __restrict__ deg){
  int total = cnt[0];
  for (int i = blockIdx.x*256+threadIdx.x; i < total; i += gridDim.x*256)
    atomicAdd(&deg[dstC[i]], 1.f);
}

__global__ void k_rsqrt(float* __restrict__ d, int n){
  int i = blockIdx.x*256+threadIdx.x; if (i<n) d[i] = rsqrtf(d[i]);
}

// level-0 scatter: thread per (edge, 4 features); F=32
__global__ void k_scatter0(const int* __restrict__ src, const int* __restrict__ dst,
                           const float* __restrict__ dinv, const float* __restrict__ H,
                           float* __restrict__ OUT){
  int i = blockIdx.x*256+threadIdx.x;
  if (i >= E_*8) return;
  int e = i>>3, q = i&7;
  int s = src[e], d = dst[e];
  float c = dinv[s]*dinv[d];
  float4 h = *(const float4*)(H + ((size_t)s<<5) + q*4);
  float* o = OUT + ((size_t)d<<5) + q*4;
  atomicAdd(o+0,h.x*c); atomicAdd(o+1,h.y*c); atomicAdd(o+2,h.z*c); atomicAdd(o+3,h.w*c);
}

// compacted-list scatter, count-driven grid-stride; F = 1<<fsh, fqsh = fsh-2
__global__ void k_scatter_cmp(const int* __restrict__ srcC, const int* __restrict__ dstC,
                              const int* __restrict__ cnt, const float* __restrict__ dinv,
                              const float* __restrict__ H, float* __restrict__ OUT,
                              int fqsh, int fsh){
  long long total = ((long long)cnt[0]) << fqsh;
  for (long long i = blockIdx.x*256+threadIdx.x; i < total; i += (long long)gridDim.x*256){
    int e = (int)(i>>fqsh), q = (int)(i & ((1<<fqsh)-1));
    int s = srcC[e], d = dstC[e];
    float c = dinv[s]*dinv[d];
    float4 h = *(const float4*)(H + ((size_t)s<<fsh) + q*4);
    float* o = OUT + ((size_t)d<<fsh) + q*4;
    atomicAdd(o+0,h.x*c); atomicAdd(o+1,h.y*c); atomicAdd(o+2,h.z*c); atomicAdd(o+3,h.w*c);
  }
}

__global__ void k_elu4(float* __restrict__ x, int n4){
  int i = blockIdx.x*256+threadIdx.x; if (i>=n4) return;
  float4 v = *(float4*)(x + (size_t)i*4);
  v.x=eluf(v.x); v.y=eluf(v.y); v.z=eluf(v.z); v.w=eluf(v.w);
  *(float4*)(x + (size_t)i*4) = v;
}

__global__ void k_score(const float* __restrict__ X, const float* __restrict__ p,
                        float* __restrict__ s, int M, int F){
  int i = blockIdx.x*256+threadIdx.x; if (i>=M) return;
  float dot=0.f, n2=0.f;
  const float* xr = X + (size_t)i*F;
  for (int f=0; f<F; ++f){ dot = fmaf(xr[f], p[f], dot); n2 = fmaf(p[f],p[f],n2); }
  s[i] = tanhf(dot / sqrtf(n2));
}

// block g sorts its npg scores descending (tie: lower index first), writes top-K
__global__ void k_topk(const float* __restrict__ score, int npg, int K,
                       int* __restrict__ perm, float* __restrict__ vals){
  __shared__ float ss[1024]; __shared__ int si[1024];
  int g = blockIdx.x, tid = threadIdx.x;
  ss[tid] = score[g*npg + tid]; si[tid] = tid;
  __syncthreads();
  for (int k=2;k<=npg;k<<=1){
    for (int j=k>>1;j>0;j>>=1){
      int ixj = tid ^ j;
      if (ixj > tid){
        float s1=ss[tid], s2=ss[ixj]; int i1=si[tid], i2=si[ixj];
        bool aAfterB = (s1 < s2) || (s1==s2 && i1 > i2);
        bool sw = ((tid & k)==0) ? aAfterB : !aAfterB;
        if (sw){ ss[tid]=s2; si[tid]=i2; ss[ixj]=s1; si[ixj]=i1; }
      }
      __syncthreads();
    }
  }
  if (tid < K){ perm[g*K+tid] = g*npg + si[tid]; vals[g*K+tid] = ss[tid]; }
}

__global__ void k_remap_set(const int* __restrict__ perm, int* __restrict__ remap, int n){
  int i = blockIdx.x*256+threadIdx.x; if (i<n) remap[perm[i]] = i;
}

// compact survivor edges from the FULL level-0 list
__global__ void k_compact_full(const int* __restrict__ src, const int* __restrict__ dst,
                               const int* __restrict__ remap,
                               int* __restrict__ srcC, int* __restrict__ dstC,
                               int* __restrict__ cnt){
  int i = blockIdx.x*256+threadIdx.x; if (i>=E_) return;
  int s = remap[src[i]], d = remap[dst[i]];
  if (s>=0 && d>=0){ int p = atomicAdd(cnt,1); srcC[p]=s; dstC[p]=d; }
}

// compact survivor edges from a parent COMPACTED list
__global__ void k_compact_cmp(const int* __restrict__ srcIn, const int* __restrict__ dstIn,
                              const int* __restrict__ cntIn, const int* __restrict__ remap,
                              int* __restrict__ srcC, int* __restrict__ dstC,
                              int* __restrict__ cnt){
  int total = cntIn[0];
  for (int i = blockIdx.x*256+threadIdx.x; i < total; i += gridDim.x*256){
    int s = remap[srcIn[i]], d = remap[dstIn[i]];
    if (s>=0 && d>=0){ int p = atomicAdd(cnt,1); srcC[p]=s; dstC[p]=d; }
  }
}

// Xout[i,:] = elu(Xin[perm[i],:] * vals[i]); F = 1<<fsh
__global__ void k_pool_gather4(const float* __restrict__ Xin, const int* __restrict__ perm,
                               const float* __restrict__ vals, float* __restrict__ Xout,
                               int Mout, int fqsh, int fsh){
  int total = Mout<<fqsh;
  int i = blockIdx.x*256+threadIdx.x; if (i>=total) return;
  int m = i>>fqsh, q = i&((1<<fqsh)-1);
  float v = vals[m];
  float4 h = *(const float4*)(Xin + ((size_t)perm[m]<<fsh) + q*4);
  float4 o; o.x=eluf(h.x*v); o.y=eluf(h.y*v); o.z=eluf(h.z*v); o.w=eluf(h.w*v);
  *(float4*)(Xout + ((size_t)m<<fsh) + q*4) = o;
}

// one-pass concat build: cat[r, 0:WD] = (remap[r]>=0 ? elu(Xd[remap[r]]) : 0),
// cat[r, WD:] = elu(Xs[r]).  Widths in float4 units.
template<int WD4,int WS4>
__global__ void k_cat(const float* __restrict__ Xd, const int* __restrict__ remap,
                      const float* __restrict__ Xs, float* __restrict__ cat, int rows){
  constexpr int W4 = WD4+WS4;
  int total = rows*W4;
  int i = blockIdx.x*256+threadIdx.x; if (i>=total) return;
  int r = i/W4, c = i - r*W4;
  float4 v;
  if (c < WD4){
    int j = remap[r];
    if (j>=0) v = *(const float4*)(Xd + (size_t)j*(WD4*4) + c*4);
    else { v.x=0.f;v.y=0.f;v.z=0.f;v.w=0.f; }
  } else {
    v = *(const float4*)(Xs + (size_t)r*(WS4*4) + (c-WD4)*4);
  }
  float4 o; o.x=eluf(v.x); o.y=eluf(v.y); o.z=eluf(v.z); o.w=eluf(v.w);
  *(float4*)(cat + (size_t)i*4) = o;
}

// per-graph global max/mean pool over (1024,32), then MLP head + log_softmax
__global__ void k_head(const float* __restrict__ x13, const float* __restrict__ Wl,
                       const float* __restrict__ Wc, const float* __restrict__ bc,
                       float* __restrict__ out){
  __shared__ float smax[256], ssum[256];
  __shared__ float gv[64], g2[64], logit[10];
  int g = blockIdx.x, t = threadIdx.x;
  int f = t & 31, r0 = t >> 5;
  float mx = -3.4e38f, sm = 0.f;
  const float* base = x13 + (size_t)g*N_*32;
  for (int r=r0; r<N_; r+=8){ float v = base[r*32+f]; mx = fmaxf(mx,v); sm += v; }
  smax[t]=mx; ssum[t]=sm; __syncthreads();
  if (t<128){ smax[t]=fmaxf(smax[t],smax[t+128]); ssum[t]+=ssum[t+128]; } __syncthreads();
  if (t<64){ smax[t]=fmaxf(smax[t],smax[t+64]); ssum[t]+=ssum[t+64]; } __syncthreads();
  if (t<32){
    float m2 = fmaxf(smax[t],smax[t+32]); float s2 = ssum[t]+ssum[t+32];
    gv[t] = eluf(m2); gv[32+t] = eluf(s2 * (1.f/N_));
  }
  __syncthreads();
  if (t<64){
    float acc=0.f;
    #pragma unroll
    for (int i2=0;i2<64;++i2) acc = fmaf(gv[i2], Wl[i2*64+t], acc);
    g2[t] = eluf(acc);
  }
  __syncthreads();
  if (t<10){
    float acc = bc[t];
    #pragma unroll
    for (int j=0;j<64;++j) acc = fmaf(g2[j], Wc[j*10+t], acc);
    logit[t] = acc;
  }
  __syncthreads();
  if (t==0){
    float m=-3.4e38f; for (int c=0;c<10;++c) m=fmaxf(m,logit[c]);
    float s=0.f; for (int c=0;c<10;++c) s += expf(logit[c]-m);
    float lse = m + logf(s);
    for (int c=0;c<10;++c) out[g*10+c] = logit[c]-lse;
  }
}

extern "C" void kernel_launch(void* const* d_in, const int* in_sizes, int n_in,
                              void* d_out, int out_size, void* d_ws, size_t ws_size,
                              hipStream_t stream){
  const float* x  = (const float*)d_in[0];
  const float* W1 = (const float*)d_in[1];
  const float* b1 = (const float*)d_in[2];
  const float* p1 = (const float*)d_in[3];
  const float* W2 = (const float*)d_in[4];
  const float* b2 = (const float*)d_in[5];
  const float* p2 = (const float*)d_in[6];
  const float* W3 = (const float*)d_in[7];
  const float* b3 = (const float*)d_in[8];
  const float* p3 = (const float*)d_in[9];
  const float* W4 = (const float*)d_in[10];
  const float* b4 = (const float*)d_in[11];
  const float* W5 = (const float*)d_in[12];
  const float* b5 = (const float*)d_in[13];
  const float* W6 = (const float*)d_in[14];
  const float* b6 = (const float*)d_in[15];
  const float* W7 = (const float*)d_in[16];
  const float* b7 = (const float*)d_in[17];
  const float* Wl = (const float*)d_in[18];
  const float* Wc = (const float*)d_in[19];
  const float* bc = (const float*)d_in[20];
  const int* src0 = (const int*)d_in[21];
  const int* dst0 = (const int*)d_in[22];
  float* out = (float*)d_out;

  char* wsp = (char*)d_ws;
  size_t off = 0;
  auto alloc = [&](size_t bytes)->char*{
    char* p = wsp + off;
    off += (bytes + 255) & ~(size_t)255;
    return p;
  };
  float* bufA = (float*)alloc((size_t)2097152*4);   // x1 / x13
  float* bufB = (float*)alloc((size_t)2097152*4);   // x3
  float* bufC = (float*)alloc((size_t)2097152*4);   // x5 / x11
  float* bufD = (float*)alloc((size_t)2097152*4);   // x7 / x9
  float* bufH = (float*)alloc((size_t)2097152*4);   // pre-norm H
  float* cat  = (float*)alloc((size_t)6291456*4);   // concat buffer (max 25.2MB)
  float* s1   = (float*)alloc((size_t)1048576*4);   // x2/x4/x6
  float* score= (float*)alloc((size_t)65536*4);
  float* vals = (float*)alloc((size_t)32768*4);
  int* idx2 = (int*)alloc((size_t)32768*4);
  int* idx4 = (int*)alloc((size_t)16384*4);
  int* idx6 = (int*)alloc((size_t)8192*4);
  int* remap2 = (int*)alloc((size_t)M0_*4);
  int* remap4 = (int*)alloc((size_t)M1_*4);
  int* remap6 = (int*)alloc((size_t)M2_*4);
  int* srcC2 = (int*)alloc((size_t)E_*4); int* dstC2=(int*)alloc((size_t)E_*4);
  int* srcC4 = (int*)alloc((size_t)E_*4); int* dstC4=(int*)alloc((size_t)E_*4);
  int* srcC6 = (int*)alloc((size_t)E_*4); int* dstC6=(int*)alloc((size_t)E_*4);
  int* cnt2 = (int*)alloc(256); int* cnt4 = (int*)alloc(256); int* cnt6 = (int*)alloc(256);
  float* dinv0 = (float*)alloc((size_t)M0_*4);
  float* dinv2 = (float*)alloc((size_t)M1_*4);
  float* dinv4 = (float*)alloc((size_t)M2_*4);
  float* dinv6 = (float*)alloc((size_t)M3_*4);

  auto NB = [](int total){ return (total+255)/256; };
  const int GS = 1024;   // grid-stride blocks for count-driven kernels

  // ---- level-0 degrees (shared by layers 1 and 7)
  k_fill<<<NB(M0_),256,0,stream>>>(dinv0, 2.f, M0_);
  k_deg_full<<<NB(E_),256,0,stream>>>(dst0, dinv0);
  k_rsqrt<<<NB(M0_),256,0,stream>>>(dinv0, M0_);

  // ---- layer 1: gcn(x) -> x1 (bufA)
  k_mm<32><<<dim3(M0_/64,1),256,0,stream>>>(x, W1, b1, dinv0, bufH, bufA, M0_, 128, 32);
  k_scatter0<<<NB(E_*8),256,0,stream>>>(src0, dst0, dinv0, bufH, bufA);
  k_elu4<<<NB(M0_*8),256,0,stream>>>(bufA, M0_*8);

  // ---- pool 1 -> x2 (s1), edges level2
  k_score<<<NB(M0_),256,0,stream>>>(bufA, p1, score, M0_, 32);
  k_topk<<<B_,1024,0,stream>>>(score, 1024, K1_, idx2, vals);
  hipMemsetAsync(remap2, 0xFF, (size_t)M0_*4, stream);
  k_remap_set<<<NB(M1_),256,0,stream>>>(idx2, remap2, M1_);
  hipMemsetAsync(cnt2, 0, 4, stream);
  k_compact_full<<<NB(E_),256,0,stream>>>(src0, dst0, remap2, srcC2, dstC2, cnt2);
  k_pool_gather4<<<NB(M1_*8),256,0,stream>>>(bufA, idx2, vals, s1, M1_, 3, 5);

  k_fill<<<NB(M1_),256,0,stream>>>(dinv2, 2.f, M1_);
  k_deg_cmp<<<GS,256,0,stream>>>(dstC2, cnt2, dinv2);
  k_rsqrt<<<NB(M1_),256,0,stream>>>(dinv2, M1_);

  // ---- layer 2: gcn(x2) -> x3 (bufB)
  k_mm<64><<<dim3(M1_/64,1),256,0,stream>>>(s1, W2, b2, dinv2, bufH, bufB, M1_, 32, 64);
  k_scatter_cmp<<<GS,256,0,stream>>>(srcC2, dstC2, cnt2, dinv2, bufH, bufB, 4, 6);
  k_elu4<<<NB(M1_*16),256,0,stream>>>(bufB, M1_*16);

  // ---- pool 2 -> x4 (s1), edges level4
  k_score<<<NB(M1_),256,0,stream>>>(bufB, p2, score, M1_, 64);
  k_topk<<<B_,512,0,stream>>>(score, 512, K2_, idx4, vals);
  hipMemsetAsync(remap4, 0xFF, (size_t)M1_*4, stream);
  k_remap_set<<<NB(M2_),256,0,stream>>>(idx4, remap4, M2_);
  hipMemsetAsync(cnt4, 0, 4, stream);
  k_compact_cmp<<<GS,256,0,stream>>>(srcC2, dstC2, cnt2, remap4, srcC4, dstC4, cnt4);
  k_pool_gather4<<<NB(M2_*16),256,0,stream>>>(bufB, idx4, vals, s1, M2_, 4, 6);

  k_fill<<<NB(M2_),256,0,stream>>>(dinv4, 2.f, M2_);
  k_deg_cmp<<<GS,256,0,stream>>>(dstC4, cnt4, dinv4);
  k_rsqrt<<<NB(M2_),256,0,stream>>>(dinv4, M2_);

  // ---- layer 3: gcn(x4) -> x5 (bufC)
  k_mm<128><<<dim3(M2_/64,1),256,0,stream>>>(s1, W3, b3, dinv4, bufH, bufC, M2_, 64, 128);
  k_scatter_cmp<<<GS,256,0,stream>>>(srcC4, dstC4, cnt4, dinv4, bufH, bufC, 5, 7);
  k_elu4<<<NB(M2_*32),256,0,stream>>>(bufC, M2_*32);

  // ---- pool 3 -> x6 (s1), edges level6
  k_score<<<NB(M2_),256,0,stream>>>(bufC, p3, score, M2_, 128);
  k_topk<<<B_,256,0,stream>>>(score, 256, K3_, idx6, vals);
  hipMemsetAsync(remap6, 0xFF, (size_t)M2_*4, stream);
  k_remap_set<<<NB(M3_),256,0,stream>>>(idx6, remap6, M3_);
  hipMemsetAsync(cnt6, 0, 4, stream);
  k_compact_cmp<<<GS,256,0,stream>>>(srcC4, dstC4, cnt4, remap6, srcC6, dstC6, cnt6);
  k_pool_gather4<<<NB(M3_*32),256,0,stream>>>(bufC, idx6, vals, s1, M3_, 5, 7);

  k_fill<<<NB(M3_),256,0,stream>>>(dinv6, 2.f, M3_);
  k_deg_cmp<<<GS,256,0,stream>>>(dstC6, cnt6, dinv6);
  k_rsqrt<<<NB(M3_),256,0,stream>>>(dinv6, M3_);

  // ---- layer 4: gcn(x6) -> x7 (bufD)
  k_mm<128><<<dim3(M3_/64,2),256,0,stream>>>(s1, W4, b4, dinv6, bufH, bufD, M3_, 128, 256);
  k_scatter_cmp<<<GS,256,0,stream>>>(srcC6, dstC6, cnt6, dinv6, bufH, bufD, 6, 8);
  k_elu4<<<NB(M3_*64),256,0,stream>>>(bufD, M3_*64);

  // ---- unpool+concat -> x8 (cat), layer 5 -> x9 (bufD)
  k_cat<64,32><<<NB(M2_*96),256,0,stream>>>(bufD, remap6, bufC, cat, M2_);
  k_mm<128><<<dim3(M2_/64,1),256,0,stream>>>(cat, W5, b5, dinv4, bufH, bufD, M2_, 384, 128);
  k_scatter_cmp<<<GS,256,0,stream>>>(srcC4, dstC4, cnt4, dinv4, bufH, bufD, 5, 7);
  k_elu4<<<NB(M2_*32),256,0,stream>>>(bufD, M2_*32);

  // ---- unpool+concat -> x10 (cat), layer 6 -> x11 (bufC)
  k_cat<32,16><<<NB(M1_*48),256,0,stream>>>(bufD, remap4, bufB, cat, M1_);
  k_mm<64><<<dim3(M1_/64,1),256,0,stream>>>(cat, W6, b6, dinv2, bufH, bufC, M1_, 192, 64);
  k_scatter_cmp<<<GS,256,0,stream>>>(srcC2, dstC2, cnt2, dinv2, bufH, bufC, 4, 6);
  k_elu4<<<NB(M1_*16),256,0,stream>>>(bufC, M1_*16);

  // ---- unpool+concat -> x12 (cat), layer 7 -> x13 (bufA)
  k_cat<16,8><<<NB(M0_*24),256,0,stream>>>(bufC, remap2, bufA, cat, M0_);
  k_mm<32><<<dim3(M0_/64,1),256,0,stream>>>(cat, W7, b7, dinv0, bufH, bufA, M0_, 96, 32);
  k_scatter0<<<NB(E_*8),256,0,stream>>>(src0, dst0, dinv0, bufH, bufA);
  k_elu4<<<NB(M0_*8),256,0,stream>>>(bufA, M0_*8);

  // ---- head
  k_head<<<B_,256,0,stream>>>(bufA, Wl, Wc, bc, out);

  (void)in_sizes; (void)n_in; (void)out_size; (void)ws_size;
}

// Round 3
// 637.359 us; speedup vs baseline: 2.1510x; 2.1510x over previous
//
#include <hip/hip_runtime.h>
#include <hip/hip_bf16.h>
#include <math.h>

#define B_ 64
#define N_ 1024
#define E_ 524288
#define K1_ 512
#define K2_ 256
#define K3_ 128
#define M0_ 65536
#define M1_ 32768
#define M2_ 16384
#define M3_ 8192

static __device__ __forceinline__ float eluf(float x){ return x > 0.f ? x : expm1f(x); }

// Tiled GEMM: block computes 64 rows x BN cols. K tiled by 32. Writes H only.
template<int BN>
__global__ __launch_bounds__(256) void k_mm(const float* __restrict__ X,
    const float* __restrict__ W, float* __restrict__ H, int M, int K, int N){
  constexpr int TX = BN/4;      // threads across cols (each owns 4 cols)
  constexpr int TY = 256/TX;
  constexpr int RM = 64/TY;     // rows per thread
  __shared__ float Xs[64][36];  // pad 36: conflict-free col reads
  __shared__ float Ws[32][BN];
  const int t = threadIdx.x;
  const int tx = t % TX, ty = t / TX;
  const int m0 = blockIdx.x*64, n0 = blockIdx.y*BN;
  float acc[RM][4];
  #pragma unroll
  for (int r=0;r<RM;++r){acc[r][0]=0.f;acc[r][1]=0.f;acc[r][2]=0.f;acc[r][3]=0.f;}
  for (int k0=0;k0<K;k0+=32){
    #pragma unroll
    for (int r=0;r<2;++r){            // 512 float4s of X tile
      int fi=r*256+t, row=fi>>3, q=fi&7;
      *(float4*)(&Xs[row][q*4]) = *(const float4*)(X + (size_t)(m0+row)*K + k0 + q*4);
    }
    #pragma unroll
    for (int r=0;r<BN/32;++r){        // 8*BN float4s of W tile
      int fi=r*256+t, row=fi/(BN/4), q=fi%(BN/4);
      *(float4*)(&Ws[row][q*4]) = *(const float4*)(W + (size_t)(k0+row)*N + n0 + q*4);
    }
    __syncthreads();
    #pragma unroll
    for (int kk=0;kk<32;++kk){
      float4 wv = *(const float4*)(&Ws[kk][tx*4]);
      #pragma unroll
      for (int r=0;r<RM;++r){
        float xv = Xs[ty*RM+r][kk];
        acc[r][0]=fmaf(xv,wv.x,acc[r][0]);
        acc[r][1]=fmaf(xv,wv.y,acc[r][1]);
        acc[r][2]=fmaf(xv,wv.z,acc[r][2]);
        acc[r][3]=fmaf(xv,wv.w,acc[r][3]);
      }
    }
    __syncthreads();
  }
  #pragma unroll
  for (int r=0;r<RM;++r){
    int m = m0 + ty*RM + r;
    float4 h; h.x=acc[r][0];h.y=acc[r][1];h.z=acc[r][2];h.w=acc[r][3];
    *(float4*)(H + (size_t)m*N + n0 + tx*4) = h;
  }
}

// ---- CSR build ----
__global__ void k_deg0(const int* __restrict__ dst, int* __restrict__ degi){
  int i = blockIdx.x*256+threadIdx.x; if (i>=E_) return;
  atomicAdd(&degi[dst[i]], 1);
}

// single-block exclusive scan of degi -> rowptr, cursor; dinv = rsqrt(deg+2)
template<int M>
__global__ __launch_bounds__(1024) void k_scan(const int* __restrict__ degi,
    int* __restrict__ rowptr, int* __restrict__ cursor, float* __restrict__ dinv){
  __shared__ int ps[1024];
  constexpr int C = M/1024;
  const int t = threadIdx.x, base = t*C;
  int sum = 0;
  for (int i=0;i<C;++i) sum += degi[base+i];
  ps[t] = sum; __syncthreads();
  for (int off=1; off<1024; off<<=1){
    int v = (t>=off) ? ps[t-off] : 0;
    __syncthreads();
    ps[t] += v;
    __syncthreads();
  }
  int run = (t==0) ? 0 : ps[t-1];
  for (int i=0;i<C;++i){
    int d = degi[base+i];
    rowptr[base+i] = run; cursor[base+i] = run;
    dinv[base+i] = rsqrtf((float)d + 2.f);
    run += d;
  }
  if (t==1023) rowptr[M] = run;
}

__global__ void k_place0(const int* __restrict__ src, const int* __restrict__ dst,
                         int* __restrict__ cursor, int* __restrict__ col){
  int i = blockIdx.x*256+threadIdx.x; if (i>=E_) return;
  int p = atomicAdd(&cursor[dst[i]], 1);
  col[p] = src[i];
}

// compact survivors from full level-0 list; also count in-degrees
__global__ void k_compact_full(const int* __restrict__ src, const int* __restrict__ dst,
                               const int* __restrict__ remap,
                               int* __restrict__ srcC, int* __restrict__ dstC,
                               int* __restrict__ cnt, int* __restrict__ degi){
  int i = blockIdx.x*256+threadIdx.x; if (i>=E_) return;
  int s = remap[src[i]], d = remap[dst[i]];
  if (s>=0 && d>=0){
    int p = atomicAdd(cnt,1); srcC[p]=s; dstC[p]=d;
    atomicAdd(&degi[d],1);
  }
}

__global__ void k_compact_cmp(const int* __restrict__ srcIn, const int* __restrict__ dstIn,
                              const int* __restrict__ cntIn, const int* __restrict__ remap,
                              int* __restrict__ srcC, int* __restrict__ dstC,
                              int* __restrict__ cnt, int* __restrict__ degi){
  int total = cntIn[0];
  for (int i = blockIdx.x*256+threadIdx.x; i < total; i += gridDim.x*256){
    int s = remap[srcIn[i]], d = remap[dstIn[i]];
    if (s>=0 && d>=0){
      int p = atomicAdd(cnt,1); srcC[p]=s; dstC[p]=d;
      atomicAdd(&degi[d],1);
    }
  }
}

__global__ void k_place_cmp(const int* __restrict__ srcC, const int* __restrict__ dstC,
                            const int* __restrict__ cnt, int* __restrict__ cursor,
                            int* __restrict__ col){
  int total = cnt[0];
  for (int i = blockIdx.x*256+threadIdx.x; i < total; i += gridDim.x*256){
    int p = atomicAdd(&cursor[dstC[i]], 1);
    col[p] = srcC[i];
  }
}

// ---- GCN aggregation: OUT[n] = elu(bias + 2*dinv[n]^2*H[n] + dinv[n]*sum dinv[s]*H[s])
template<int F>
__global__ __launch_bounds__(256) void k_gather(const int* __restrict__ rowptr,
    const int* __restrict__ col, const float* __restrict__ dinv,
    const float* __restrict__ H, const float* __restrict__ bias,
    float* __restrict__ OUT, int M){
  constexpr int FQ = F/4;
  int i = blockIdx.x*256+threadIdx.x;
  if (i >= M*FQ) return;
  int n = i/FQ, q = i - (i/FQ)*FQ;
  int beg = rowptr[n], end = rowptr[n+1];
  float4 acc; acc.x=0.f;acc.y=0.f;acc.z=0.f;acc.w=0.f;
  for (int j=beg;j<end;++j){
    int s = col[j];
    float c = dinv[s];
    float4 h = *(const float4*)(H + (size_t)s*F + q*4);
    acc.x=fmaf(c,h.x,acc.x); acc.y=fmaf(c,h.y,acc.y);
    acc.z=fmaf(c,h.z,acc.z); acc.w=fmaf(c,h.w,acc.w);
  }
  float dn = dinv[n];
  float sc = 2.f*dn*dn;
  float4 hn = *(const float4*)(H + (size_t)n*F + q*4);
  float4 bv = *(const float4*)(bias + q*4);
  float4 o;
  o.x = eluf(fmaf(sc,hn.x,fmaf(dn,acc.x,bv.x)));
  o.y = eluf(fmaf(sc,hn.y,fmaf(dn,acc.y,bv.y)));
  o.z = eluf(fmaf(sc,hn.z,fmaf(dn,acc.z,bv.z)));
  o.w = eluf(fmaf(sc,hn.w,fmaf(dn,acc.w,bv.w)));
  *(float4*)(OUT + (size_t)n*F + q*4) = o;
}

__global__ void k_score(const float* __restrict__ X, const float* __restrict__ p,
                        float* __restrict__ s, int M, int F){
  int i = blockIdx.x*256+threadIdx.x; if (i>=M) return;
  float dot=0.f, n2=0.f;
  const float* xr = X + (size_t)i*F;
  for (int f=0; f<F; ++f){ dot = fmaf(xr[f], p[f], dot); n2 = fmaf(p[f],p[f],n2); }
  s[i] = tanhf(dot / sqrtf(n2));
}

// block g sorts its npg scores descending (tie: lower index first), writes top-K
__global__ void k_topk(const float* __restrict__ score, int npg, int K,
                       int* __restrict__ perm, float* __restrict__ vals){
  __shared__ float ss[1024]; __shared__ int si[1024];
  int g = blockIdx.x, tid = threadIdx.x;
  ss[tid] = score[g*npg + tid]; si[tid] = tid;
  __syncthreads();
  for (int k=2;k<=npg;k<<=1){
    for (int j=k>>1;j>0;j>>=1){
      int ixj = tid ^ j;
      if (ixj > tid){
        float s1=ss[tid], s2=ss[ixj]; int i1=si[tid], i2=si[ixj];
        bool aAfterB = (s1 < s2) || (s1==s2 && i1 > i2);
        bool sw = ((tid & k)==0) ? aAfterB : !aAfterB;
        if (sw){ ss[tid]=s2; si[tid]=i2; ss[ixj]=s1; si[ixj]=i1; }
      }
      __syncthreads();
    }
  }
  if (tid < K){ perm[g*K+tid] = g*npg + si[tid]; vals[g*K+tid] = ss[tid]; }
}

__global__ void k_remap_set(const int* __restrict__ perm, int* __restrict__ remap, int n){
  int i = blockIdx.x*256+threadIdx.x; if (i<n) remap[perm[i]] = i;
}

// Xout[i,:] = elu(Xin[perm[i],:] * vals[i]); F = 1<<fsh
__global__ void k_pool_gather4(const float* __restrict__ Xin, const int* __restrict__ perm,
                               const float* __restrict__ vals, float* __restrict__ Xout,
                               int Mout, int fqsh, int fsh){
  int total = Mout<<fqsh;
  int i = blockIdx.x*256+threadIdx.x; if (i>=total) return;
  int m = i>>fqsh, q = i&((1<<fqsh)-1);
  float v = vals[m];
  float4 h = *(const float4*)(Xin + ((size_t)perm[m]<<fsh) + q*4);
  float4 o; o.x=eluf(h.x*v); o.y=eluf(h.y*v); o.z=eluf(h.z*v); o.w=eluf(h.w*v);
  *(float4*)(Xout + ((size_t)m<<fsh) + q*4) = o;
}

// one-pass concat build: cat[r,0:WD]=(remap[r]>=0?elu(Xd[remap[r]]):0), cat[r,WD:]=elu(Xs[r])
template<int WD4,int WS4>
__global__ void k_cat(const float* __restrict__ Xd, const int* __restrict__ remap,
                      const float* __restrict__ Xs, float* __restrict__ cat, int rows){
  constexpr int W4 = WD4+WS4;
  int total = rows*W4;
  int i = blockIdx.x*256+threadIdx.x; if (i>=total) return;
  int r = i/W4, c = i - r*W4;
  float4 v;
  if (c < WD4){
    int j = remap[r];
    if (j>=0) v = *(const float4*)(Xd + (size_t)j*(WD4*4) + c*4);
    else { v.x=0.f;v.y=0.f;v.z=0.f;v.w=0.f; }
  } else {
    v = *(const float4*)(Xs + (size_t)r*(WS4*4) + (c-WD4)*4);
  }
  float4 o; o.x=eluf(v.x); o.y=eluf(v.y); o.z=eluf(v.z); o.w=eluf(v.w);
  *(float4*)(cat + (size_t)i*4) = o;
}

// per-graph global max/mean pool over (1024,32), then MLP head + log_softmax
__global__ void k_head(const float* __restrict__ x13, const float* __restrict__ Wl,
                       const float* __restrict__ Wc, const float* __restrict__ bc,
                       float* __restrict__ out){
  __shared__ float smax[256], ssum[256];
  __shared__ float gv[64], g2[64], logit[10];
  int g = blockIdx.x, t = threadIdx.x;
  int f = t & 31, r0 = t >> 5;
  float mx = -3.4e38f, sm = 0.f;
  const float* base = x13 + (size_t)g*N_*32;
  for (int r=r0; r<N_; r+=8){ float v = base[r*32+f]; mx = fmaxf(mx,v); sm += v; }
  smax[t]=mx; ssum[t]=sm; __syncthreads();
  if (t<128){ smax[t]=fmaxf(smax[t],smax[t+128]); ssum[t]+=ssum[t+128]; } __syncthreads();
  if (t<64){ smax[t]=fmaxf(smax[t],smax[t+64]); ssum[t]+=ssum[t+64]; } __syncthreads();
  if (t<32){
    float m2 = fmaxf(smax[t],smax[t+32]); float s2 = ssum[t]+ssum[t+32];
    gv[t] = eluf(m2); gv[32+t] = eluf(s2 * (1.f/N_));
  }
  __syncthreads();
  if (t<64){
    float acc=0.f;
    #pragma unroll
    for (int i2=0;i2<64;++i2) acc = fmaf(gv[i2], Wl[i2*64+t], acc);
    g2[t] = eluf(acc);
  }
  __syncthreads();
  if (t<10){
    float acc = bc[t];
    #pragma unroll
    for (int j=0;j<64;++j) acc = fmaf(g2[j], Wc[j*10+t], acc);
    logit[t] = acc;
  }
  __syncthreads();
  if (t==0){
    float m=-3.4e38f; for (int c=0;c<10;++c) m=fmaxf(m,logit[c]);
    float s=0.f; for (int c=0;c<10;++c) s += expf(logit[c]-m);
    float lse = m + logf(s);
    for (int c=0;c<10;++c) out[g*10+c] = logit[c]-lse;
  }
}

extern "C" void kernel_launch(void* const* d_in, const int* in_sizes, int n_in,
                              void* d_out, int out_size, void* d_ws, size_t ws_size,
                              hipStream_t stream){
  const float* x  = (const float*)d_in[0];
  const float* W1 = (const float*)d_in[1];
  const float* b1 = (const float*)d_in[2];
  const float* p1 = (const float*)d_in[3];
  const float* W2 = (const float*)d_in[4];
  const float* b2 = (const float*)d_in[5];
  const float* p2 = (const float*)d_in[6];
  const float* W3 = (const float*)d_in[7];
  const float* b3 = (const float*)d_in[8];
  const float* p3 = (const float*)d_in[9];
  const float* W4 = (const float*)d_in[10];
  const float* b4 = (const float*)d_in[11];
  const float* W5 = (const float*)d_in[12];
  const float* b5 = (const float*)d_in[13];
  const float* W6 = (const float*)d_in[14];
  const float* b6 = (const float*)d_in[15];
  const float* W7 = (const float*)d_in[16];
  const float* b7 = (const float*)d_in[17];
  const float* Wl = (const float*)d_in[18];
  const float* Wc = (const float*)d_in[19];
  const float* bc = (const float*)d_in[20];
  const int* src0 = (const int*)d_in[21];
  const int* dst0 = (const int*)d_in[22];
  float* out = (float*)d_out;

  char* wsp = (char*)d_ws;
  size_t off = 0;
  auto alloc = [&](size_t bytes)->char*{
    char* p = wsp + off;
    off += (bytes + 255) & ~(size_t)255;
    return p;
  };
  float* bufA = (float*)alloc((size_t)2097152*4);   // x1 / x13
  float* bufB = (float*)alloc((size_t)2097152*4);   // x3
  float* bufC = (float*)alloc((size_t)2097152*4);   // x5 / x11
  float* bufD = (float*)alloc((size_t)2097152*4);   // x7 / x9
  float* bufH = (float*)alloc((size_t)2097152*4);   // pre-norm H
  float* cat  = (float*)alloc((size_t)6291456*4);   // concat buffer
  float* s1   = (float*)alloc((size_t)1048576*4);   // x2/x4/x6
  float* score= (float*)alloc((size_t)65536*4);
  float* vals = (float*)alloc((size_t)32768*4);
  int* idx2 = (int*)alloc((size_t)32768*4);
  int* idx4 = (int*)alloc((size_t)16384*4);
  int* idx6 = (int*)alloc((size_t)8192*4);
  int* remap2 = (int*)alloc((size_t)M0_*4);
  int* remap4 = (int*)alloc((size_t)M1_*4);
  int* remap6 = (int*)alloc((size_t)M2_*4);
  int* srcC2 = (int*)alloc((size_t)E_*4); int* dstC2=(int*)alloc((size_t)E_*4);
  int* srcC4 = (int*)alloc((size_t)E_*4); int* dstC4=(int*)alloc((size_t)E_*4);
  int* srcC6 = (int*)alloc((size_t)E_*4); int* dstC6=(int*)alloc((size_t)E_*4);
  int* col0 = (int*)alloc((size_t)E_*4);
  int* col2 = (int*)alloc((size_t)E_*4);
  int* col4 = (int*)alloc((size_t)E_*4);
  int* col6 = (int*)alloc((size_t)E_*4);
  int* rowptr0 = (int*)alloc((size_t)(M0_+1)*4); int* cursor0 = (int*)alloc((size_t)M0_*4);
  int* rowptr2 = (int*)alloc((size_t)(M1_+1)*4); int* cursor2 = (int*)alloc((size_t)M1_*4);
  int* rowptr4 = (int*)alloc((size_t)(M2_+1)*4); int* cursor4 = (int*)alloc((size_t)M2_*4);
  int* rowptr6 = (int*)alloc((size_t)(M3_+1)*4); int* cursor6 = (int*)alloc((size_t)M3_*4);
  int* degi0 = (int*)alloc((size_t)M0_*4);
  int* degi2 = (int*)alloc((size_t)M1_*4);
  int* degi4 = (int*)alloc((size_t)M2_*4);
  int* degi6 = (int*)alloc((size_t)M3_*4);
  int* cnt2 = (int*)alloc(256); int* cnt4 = (int*)alloc(256); int* cnt6 = (int*)alloc(256);
  float* dinv0 = (float*)alloc((size_t)M0_*4);
  float* dinv2 = (float*)alloc((size_t)M1_*4);
  float* dinv4 = (float*)alloc((size_t)M2_*4);
  float* dinv6 = (float*)alloc((size_t)M3_*4);

  auto NB = [](int total){ return (total+255)/256; };
  const int GS = 512;   // grid-stride blocks for count-driven kernels

  // ---- level-0 CSR (shared by layers 1 and 7)
  hipMemsetAsync(degi0, 0, (size_t)M0_*4, stream);
  k_deg0<<<NB(E_),256,0,stream>>>(dst0, degi0);
  k_scan<M0_><<<1,1024,0,stream>>>(degi0, rowptr0, cursor0, dinv0);
  k_place0<<<NB(E_),256,0,stream>>>(src0, dst0, cursor0, col0);

  // ---- layer 1: gcn(x) -> x1 (bufA)
  k_mm<32><<<dim3(M0_/64,1),256,0,stream>>>(x, W1, bufH, M0_, 128, 32);
  k_gather<32><<<NB(M0_*8),256,0,stream>>>(rowptr0, col0, dinv0, bufH, b1, bufA, M0_);

  // ---- pool 1 -> x2 (s1), level-2 edges + CSR
  k_score<<<NB(M0_),256,0,stream>>>(bufA, p1, score, M0_, 32);
  k_topk<<<B_,1024,0,stream>>>(score, 1024, K1_, idx2, vals);
  hipMemsetAsync(remap2, 0xFF, (size_t)M0_*4, stream);
  k_remap_set<<<NB(M1_),256,0,stream>>>(idx2, remap2, M1_);
  hipMemsetAsync(cnt2, 0, 4, stream);
  hipMemsetAsync(degi2, 0, (size_t)M1_*4, stream);
  k_compact_full<<<NB(E_),256,0,stream>>>(src0, dst0, remap2, srcC2, dstC2, cnt2, degi2);
  k_scan<M1_><<<1,1024,0,stream>>>(degi2, rowptr2, cursor2, dinv2);
  k_place_cmp<<<GS,256,0,stream>>>(srcC2, dstC2, cnt2, cursor2, col2);
  k_pool_gather4<<<NB(M1_*8),256,0,stream>>>(bufA, idx2, vals, s1, M1_, 3, 5);

  // ---- layer 2: gcn(x2) -> x3 (bufB)
  k_mm<64><<<dim3(M1_/64,1),256,0,stream>>>(s1, W2, bufH, M1_, 32, 64);
  k_gather<64><<<NB(M1_*16),256,0,stream>>>(rowptr2, col2, dinv2, bufH, b2, bufB, M1_);

  // ---- pool 2 -> x4 (s1), level-4 edges + CSR
  k_score<<<NB(M1_),256,0,stream>>>(bufB, p2, score, M1_, 64);
  k_topk<<<B_,512,0,stream>>>(score, 512, K2_, idx4, vals);
  hipMemsetAsync(remap4, 0xFF, (size_t)M1_*4, stream);
  k_remap_set<<<NB(M2_),256,0,stream>>>(idx4, remap4, M2_);
  hipMemsetAsync(cnt4, 0, 4, stream);
  hipMemsetAsync(degi4, 0, (size_t)M2_*4, stream);
  k_compact_cmp<<<GS,256,0,stream>>>(srcC2, dstC2, cnt2, remap4, srcC4, dstC4, cnt4, degi4);
  k_scan<M2_><<<1,1024,0,stream>>>(degi4, rowptr4, cursor4, dinv4);
  k_place_cmp<<<GS,256,0,stream>>>(srcC4, dstC4, cnt4, cursor4, col4);
  k_pool_gather4<<<NB(M2_*16),256,0,stream>>>(bufB, idx4, vals, s1, M2_, 4, 6);

  // ---- layer 3: gcn(x4) -> x5 (bufC)
  k_mm<128><<<dim3(M2_/64,1),256,0,stream>>>(s1, W3, bufH, M2_, 64, 128);
  k_gather<128><<<NB(M2_*32),256,0,stream>>>(rowptr4, col4, dinv4, bufH, b3, bufC, M2_);

  // ---- pool 3 -> x6 (s1), level-6 edges + CSR
  k_score<<<NB(M2_),256,0,stream>>>(bufC, p3, score, M2_, 128);
  k_topk<<<B_,256,0,stream>>>(score, 256, K3_, idx6, vals);
  hipMemsetAsync(remap6, 0xFF, (size_t)M2_*4, stream);
  k_remap_set<<<NB(M3_),256,0,stream>>>(idx6, remap6, M3_);
  hipMemsetAsync(cnt6, 0, 4, stream);
  hipMemsetAsync(degi6, 0, (size_t)M3_*4, stream);
  k_compact_cmp<<<GS,256,0,stream>>>(srcC4, dstC4, cnt4, remap6, srcC6, dstC6, cnt6, degi6);
  k_scan<M3_><<<1,1024,0,stream>>>(degi6, rowptr6, cursor6, dinv6);
  k_place_cmp<<<GS,256,0,stream>>>(srcC6, dstC6, cnt6, cursor6, col6);
  k_pool_gather4<<<NB(M3_*32),256,0,stream>>>(bufC, idx6, vals, s1, M3_, 5, 7);

  // ---- layer 4: gcn(x6) -> x7 (bufD)
  k_mm<128><<<dim3(M3_/64,2),256,0,stream>>>(s1, W4, bufH, M3_, 128, 256);
  k_gather<256><<<NB(M3_*64),256,0,stream>>>(rowptr6, col6, dinv6, bufH, b4, bufD, M3_);

  // ---- unpool+concat -> x8 (cat), layer 5 -> x9 (bufD)
  k_cat<64,32><<<NB(M2_*96),256,0,stream>>>(bufD, remap6, bufC, cat, M2_);
  k_mm<128><<<dim3(M2_/64,1),256,0,stream>>>(cat, W5, bufH, M2_, 384, 128);
  k_gather<128><<<NB(M2_*32),256,0,stream>>>(rowptr4, col4, dinv4, bufH, b5, bufD, M2_);

  // ---- unpool+concat -> x10 (cat), layer 6 -> x11 (bufC)
  k_cat<32,16><<<NB(M1_*48),256,0,stream>>>(bufD, remap4, bufB, cat, M1_);
  k_mm<64><<<dim3(M1_/64,1),256,0,stream>>>(cat, W6, bufH, M1_, 192, 64);
  k_gather<64><<<NB(M1_*16),256,0,stream>>>(rowptr2, col2, dinv2, bufH, b6, bufC, M1_);

  // ---- unpool+concat -> x12 (cat), layer 7 -> x13 (bufA)
  k_cat<16,8><<<NB(M0_*24),256,0,stream>>>(bufC, remap2, bufA, cat, M0_);
  k_mm<32><<<dim3(M0_/64,1),256,0,stream>>>(cat, W7, bufH, M0_, 96, 32);
  k_gather<32><<<NB(M0_*8),256,0,stream>>>(rowptr0, col0, dinv0, bufH, b7, bufA, M0_);

  // ---- head
  k_head<<<B_,256,0,stream>>>(bufA, Wl, Wc, bc, out);

  (void)in_sizes; (void)n_in; (void)out_size; (void)ws_size;
}

// Round 4
// 510.479 us; speedup vs baseline: 2.6857x; 1.2486x over previous
//
#include <hip/hip_runtime.h>
#include <hip/hip_bf16.h>
#include <math.h>

#define B_ 64
#define N_ 1024
#define E_ 524288
#define K1_ 512
#define K2_ 256
#define K3_ 128
#define M0_ 65536
#define M1_ 32768
#define M2_ 16384
#define M3_ 8192

static __device__ __forceinline__ float eluf(float x){ return x > 0.f ? x : expm1f(x); }

// Tiled GEMM: block computes 64 rows x BN cols. K tiled by 32. Writes H only.
template<int BN>
__global__ __launch_bounds__(256) void k_mm(const float* __restrict__ X,
    const float* __restrict__ W, float* __restrict__ H, int M, int K, int N){
  constexpr int TX = BN/4;      // threads across cols (each owns 4 cols)
  constexpr int TY = 256/TX;
  constexpr int RM = 64/TY;     // rows per thread
  __shared__ float Xs[64][36];  // pad 36: conflict-free col reads
  __shared__ float Ws[32][BN];
  const int t = threadIdx.x;
  const int tx = t % TX, ty = t / TX;
  const int m0 = blockIdx.x*64, n0 = blockIdx.y*BN;
  float acc[RM][4];
  #pragma unroll
  for (int r=0;r<RM;++r){acc[r][0]=0.f;acc[r][1]=0.f;acc[r][2]=0.f;acc[r][3]=0.f;}
  for (int k0=0;k0<K;k0+=32){
    #pragma unroll
    for (int r=0;r<2;++r){            // 512 float4s of X tile
      int fi=r*256+t, row=fi>>3, q=fi&7;
      *(float4*)(&Xs[row][q*4]) = *(const float4*)(X + (size_t)(m0+row)*K + k0 + q*4);
    }
    #pragma unroll
    for (int r=0;r<BN/32;++r){        // 8*BN float4s of W tile
      int fi=r*256+t, row=fi/(BN/4), q=fi%(BN/4);
      *(float4*)(&Ws[row][q*4]) = *(const float4*)(W + (size_t)(k0+row)*N + n0 + q*4);
    }
    __syncthreads();
    #pragma unroll
    for (int kk=0;kk<32;++kk){
      float4 wv = *(const float4*)(&Ws[kk][tx*4]);
      #pragma unroll
      for (int r=0;r<RM;++r){
        float xv = Xs[ty*RM+r][kk];
        acc[r][0]=fmaf(xv,wv.x,acc[r][0]);
        acc[r][1]=fmaf(xv,wv.y,acc[r][1]);
        acc[r][2]=fmaf(xv,wv.z,acc[r][2]);
        acc[r][3]=fmaf(xv,wv.w,acc[r][3]);
      }
    }
    __syncthreads();
  }
  #pragma unroll
  for (int r=0;r<RM;++r){
    int m = m0 + ty*RM + r;
    float4 h; h.x=acc[r][0];h.y=acc[r][1];h.z=acc[r][2];h.w=acc[r][3];
    *(float4*)(H + (size_t)m*N + n0 + tx*4) = h;
  }
}

// ---- CSR build (all atomics SPREAD across node addresses; no shared counter) ----
__global__ void k_deg0(const int* __restrict__ dst, int* __restrict__ degi){
  int i = blockIdx.x*256+threadIdx.x; if (i>=E_) return;
  atomicAdd(&degi[dst[i]], 1);
}

__global__ void k_place0(const int* __restrict__ src, const int* __restrict__ dst,
                         int* __restrict__ cursor, int* __restrict__ col){
  int i = blockIdx.x*256+threadIdx.x; if (i>=E_) return;
  int p = atomicAdd(&cursor[dst[i]], 1);
  col[p] = src[i];
}

// degree pass over FULL level-0 edge list through a composed level0->levelL remap
__global__ void k_deg_rm(const int* __restrict__ src, const int* __restrict__ dst,
                         const int* __restrict__ rm, int* __restrict__ degi){
  int i = blockIdx.x*256+threadIdx.x; if (i>=E_) return;
  int s = rm[src[i]], d = rm[dst[i]];
  if (s>=0 && d>=0) atomicAdd(&degi[d], 1);
}

__global__ void k_place_rm(const int* __restrict__ src, const int* __restrict__ dst,
                           const int* __restrict__ rm, int* __restrict__ cursor,
                           int* __restrict__ col){
  int i = blockIdx.x*256+threadIdx.x; if (i>=E_) return;
  int s = rm[src[i]], d = rm[dst[i]];
  if (s>=0 && d>=0){ int p = atomicAdd(&cursor[d],1); col[p]=s; }
}

// rmOut = rmB ∘ rmA  (level0->L2 via rmA, then L2->L3 via rmB)
__global__ void k_compose(const int* __restrict__ rmA, const int* __restrict__ rmB,
                          int* __restrict__ rmOut, int n){
  int i = blockIdx.x*256+threadIdx.x; if (i>=n) return;
  int a = rmA[i];
  rmOut[i] = (a>=0) ? rmB[a] : -1;
}

// single-block exclusive scan of degi -> rowptr, cursor; dinv = rsqrt(deg+2)
template<int M>
__global__ __launch_bounds__(1024) void k_scan(const int* __restrict__ degi,
    int* __restrict__ rowptr, int* __restrict__ cursor, float* __restrict__ dinv){
  __shared__ int ps[1024];
  constexpr int C = M/1024;
  const int t = threadIdx.x, base = t*C;
  int sum = 0;
  for (int i=0;i<C;++i) sum += degi[base+i];
  ps[t] = sum; __syncthreads();
  for (int off=1; off<1024; off<<=1){
    int v = (t>=off) ? ps[t-off] : 0;
    __syncthreads();
    ps[t] += v;
    __syncthreads();
  }
  int run = (t==0) ? 0 : ps[t-1];
  for (int i=0;i<C;++i){
    int d = degi[base+i];
    rowptr[base+i] = run; cursor[base+i] = run;
    dinv[base+i] = rsqrtf((float)d + 2.f);
    run += d;
  }
  if (t==1023) rowptr[M] = run;
}

// ---- GCN aggregation: OUT[n] = elu(bias + 2*dinv[n]^2*H[n] + dinv[n]*sum dinv[s]*H[s])
template<int F>
__global__ __launch_bounds__(256) void k_gather(const int* __restrict__ rowptr,
    const int* __restrict__ col, const float* __restrict__ dinv,
    const float* __restrict__ H, const float* __restrict__ bias,
    float* __restrict__ OUT, int M){
  constexpr int FQ = F/4;
  int i = blockIdx.x*256+threadIdx.x;
  if (i >= M*FQ) return;
  int n = i/FQ, q = i - (i/FQ)*FQ;
  int beg = rowptr[n], end = rowptr[n+1];
  float4 acc; acc.x=0.f;acc.y=0.f;acc.z=0.f;acc.w=0.f;
  for (int j=beg;j<end;++j){
    int s = col[j];
    float c = dinv[s];
    float4 h = *(const float4*)(H + (size_t)s*F + q*4);
    acc.x=fmaf(c,h.x,acc.x); acc.y=fmaf(c,h.y,acc.y);
    acc.z=fmaf(c,h.z,acc.z); acc.w=fmaf(c,h.w,acc.w);
  }
  float dn = dinv[n];
  float sc = 2.f*dn*dn;
  float4 hn = *(const float4*)(H + (size_t)n*F + q*4);
  float4 bv = *(const float4*)(bias + q*4);
  float4 o;
  o.x = eluf(fmaf(sc,hn.x,fmaf(dn,acc.x,bv.x)));
  o.y = eluf(fmaf(sc,hn.y,fmaf(dn,acc.y,bv.y)));
  o.z = eluf(fmaf(sc,hn.z,fmaf(dn,acc.z,bv.z)));
  o.w = eluf(fmaf(sc,hn.w,fmaf(dn,acc.w,bv.w)));
  *(float4*)(OUT + (size_t)n*F + q*4) = o;
}

__global__ void k_score(const float* __restrict__ X, const float* __restrict__ p,
                        float* __restrict__ s, int M, int F){
  int i = blockIdx.x*256+threadIdx.x; if (i>=M) return;
  float dot=0.f, n2=0.f;
  const float* xr = X + (size_t)i*F;
  for (int f=0; f<F; ++f){ dot = fmaf(xr[f], p[f], dot); n2 = fmaf(p[f],p[f],n2); }
  s[i] = tanhf(dot / sqrtf(n2));
}

// block g sorts its npg scores descending (tie: lower index first), writes top-K
__global__ void k_topk(const float* __restrict__ score, int npg, int K,
                       int* __restrict__ perm, float* __restrict__ vals){
  __shared__ float ss[1024]; __shared__ int si[1024];
  int g = blockIdx.x, tid = threadIdx.x;
  ss[tid] = score[g*npg + tid]; si[tid] = tid;
  __syncthreads();
  for (int k=2;k<=npg;k<<=1){
    for (int j=k>>1;j>0;j>>=1){
      int ixj = tid ^ j;
      if (ixj > tid){
        float s1=ss[tid], s2=ss[ixj]; int i1=si[tid], i2=si[ixj];
        bool aAfterB = (s1 < s2) || (s1==s2 && i1 > i2);
        bool sw = ((tid & k)==0) ? aAfterB : !aAfterB;
        if (sw){ ss[tid]=s2; si[tid]=i2; ss[ixj]=s1; si[ixj]=i1; }
      }
      __syncthreads();
    }
  }
  if (tid < K){ perm[g*K+tid] = g*npg + si[tid]; vals[g*K+tid] = ss[tid]; }
}

__global__ void k_remap_set(const int* __restrict__ perm, int* __restrict__ remap, int n){
  int i = blockIdx.x*256+threadIdx.x; if (i<n) remap[perm[i]] = i;
}

// Xout[i,:] = elu(Xin[perm[i],:] * vals[i]); F = 1<<fsh
__global__ void k_pool_gather4(const float* __restrict__ Xin, const int* __restrict__ perm,
                               const float* __restrict__ vals, float* __restrict__ Xout,
                               int Mout, int fqsh, int fsh){
  int total = Mout<<fqsh;
  int i = blockIdx.x*256+threadIdx.x; if (i>=total) return;
  int m = i>>fqsh, q = i&((1<<fqsh)-1);
  float v = vals[m];
  float4 h = *(const float4*)(Xin + ((size_t)perm[m]<<fsh) + q*4);
  float4 o; o.x=eluf(h.x*v); o.y=eluf(h.y*v); o.z=eluf(h.z*v); o.w=eluf(h.w*v);
  *(float4*)(Xout + ((size_t)m<<fsh) + q*4) = o;
}

// one-pass concat build: cat[r,0:WD]=(remap[r]>=0?elu(Xd[remap[r]]):0), cat[r,WD:]=elu(Xs[r])
template<int WD4,int WS4>
__global__ void k_cat(const float* __restrict__ Xd, const int* __restrict__ remap,
                      const float* __restrict__ Xs, float* __restrict__ cat, int rows){
  constexpr int W4 = WD4+WS4;
  int total = rows*W4;
  int i = blockIdx.x*256+threadIdx.x; if (i>=total) return;
  int r = i/W4, c = i - r*W4;
  float4 v;
  if (c < WD4){
    int j = remap[r];
    if (j>=0) v = *(const float4*)(Xd + (size_t)j*(WD4*4) + c*4);
    else { v.x=0.f;v.y=0.f;v.z=0.f;v.w=0.f; }
  } else {
    v = *(const float4*)(Xs + (size_t)r*(WS4*4) + (c-WD4)*4);
  }
  float4 o; o.x=eluf(v.x); o.y=eluf(v.y); o.z=eluf(v.z); o.w=eluf(v.w);
  *(float4*)(cat + (size_t)i*4) = o;
}

// per-graph global max/mean pool over (1024,32), then MLP head + log_softmax
__global__ void k_head(const float* __restrict__ x13, const float* __restrict__ Wl,
                       const float* __restrict__ Wc, const float* __restrict__ bc,
                       float* __restrict__ out){
  __shared__ float smax[256], ssum[256];
  __shared__ float gv[64], g2[64], logit[10];
  int g = blockIdx.x, t = threadIdx.x;
  int f = t & 31, r0 = t >> 5;
  float mx = -3.4e38f, sm = 0.f;
  const float* base = x13 + (size_t)g*N_*32;
  for (int r=r0; r<N_; r+=8){ float v = base[r*32+f]; mx = fmaxf(mx,v); sm += v; }
  smax[t]=mx; ssum[t]=sm; __syncthreads();
  if (t<128){ smax[t]=fmaxf(smax[t],smax[t+128]); ssum[t]+=ssum[t+128]; } __syncthreads();
  if (t<64){ smax[t]=fmaxf(smax[t],smax[t+64]); ssum[t]+=ssum[t+64]; } __syncthreads();
  if (t<32){
    float m2 = fmaxf(smax[t],smax[t+32]); float s2 = ssum[t]+ssum[t+32];
    gv[t] = eluf(m2); gv[32+t] = eluf(s2 * (1.f/N_));
  }
  __syncthreads();
  if (t<64){
    float acc=0.f;
    #pragma unroll
    for (int i2=0;i2<64;++i2) acc = fmaf(gv[i2], Wl[i2*64+t], acc);
    g2[t] = eluf(acc);
  }
  __syncthreads();
  if (t<10){
    float acc = bc[t];
    #pragma unroll
    for (int j=0;j<64;++j) acc = fmaf(g2[j], Wc[j*10+t], acc);
    logit[t] = acc;
  }
  __syncthreads();
  if (t==0){
    float m=-3.4e38f; for (int c=0;c<10;++c) m=fmaxf(m,logit[c]);
    float s=0.f; for (int c=0;c<10;++c) s += expf(logit[c]-m);
    float lse = m + logf(s);
    for (int c=0;c<10;++c) out[g*10+c] = logit[c]-lse;
  }
}

extern "C" void kernel_launch(void* const* d_in, const int* in_sizes, int n_in,
                              void* d_out, int out_size, void* d_ws, size_t ws_size,
                              hipStream_t stream){
  const float* x  = (const float*)d_in[0];
  const float* W1 = (const float*)d_in[1];
  const float* b1 = (const float*)d_in[2];
  const float* p1 = (const float*)d_in[3];
  const float* W2 = (const float*)d_in[4];
  const float* b2 = (const float*)d_in[5];
  const float* p2 = (const float*)d_in[6];
  const float* W3 = (const float*)d_in[7];
  const float* b3 = (const float*)d_in[8];
  const float* p3 = (const float*)d_in[9];
  const float* W4 = (const float*)d_in[10];
  const float* b4 = (const float*)d_in[11];
  const float* W5 = (const float*)d_in[12];
  const float* b5 = (const float*)d_in[13];
  const float* W6 = (const float*)d_in[14];
  const float* b6 = (const float*)d_in[15];
  const float* W7 = (const float*)d_in[16];
  const float* b7 = (const float*)d_in[17];
  const float* Wl = (const float*)d_in[18];
  const float* Wc = (const float*)d_in[19];
  const float* bc = (const float*)d_in[20];
  const int* src0 = (const int*)d_in[21];
  const int* dst0 = (const int*)d_in[22];
  float* out = (float*)d_out;

  char* wsp = (char*)d_ws;
  size_t off = 0;
  auto alloc = [&](size_t bytes)->char*{
    char* p = wsp + off;
    off += (bytes + 255) & ~(size_t)255;
    return p;
  };
  float* bufA = (float*)alloc((size_t)2097152*4);   // x1 / x13
  float* bufB = (float*)alloc((size_t)2097152*4);   // x3
  float* bufC = (float*)alloc((size_t)2097152*4);   // x5 / x11
  float* bufD = (float*)alloc((size_t)2097152*4);   // x7 / x9
  float* bufH = (float*)alloc((size_t)2097152*4);   // pre-norm H
  float* cat  = (float*)alloc((size_t)6291456*4);   // concat buffer
  float* s1   = (float*)alloc((size_t)1048576*4);   // x2/x4/x6
  float* score= (float*)alloc((size_t)65536*4);
  float* vals = (float*)alloc((size_t)32768*4);
  int* idx2 = (int*)alloc((size_t)32768*4);
  int* idx4 = (int*)alloc((size_t)16384*4);
  int* idx6 = (int*)alloc((size_t)8192*4);
  int* remap2 = (int*)alloc((size_t)M0_*4);   // level2 idx over level0 nodes
  int* remap4 = (int*)alloc((size_t)M1_*4);   // level4 idx over level2 nodes
  int* remap6 = (int*)alloc((size_t)M2_*4);   // level6 idx over level4 nodes
  int* rm04   = (int*)alloc((size_t)M0_*4);   // composed level0 -> level4
  int* rm06   = (int*)alloc((size_t)M0_*4);   // composed level0 -> level6
  int* col0 = (int*)alloc((size_t)E_*4);
  int* col2 = (int*)alloc((size_t)E_*4);
  int* col4 = (int*)alloc((size_t)E_*4);
  int* col6 = (int*)alloc((size_t)E_*4);
  int* rowptr0 = (int*)alloc((size_t)(M0_+1)*4); int* cursor0 = (int*)alloc((size_t)M0_*4);
  int* rowptr2 = (int*)alloc((size_t)(M1_+1)*4); int* cursor2 = (int*)alloc((size_t)M1_*4);
  int* rowptr4 = (int*)alloc((size_t)(M2_+1)*4); int* cursor4 = (int*)alloc((size_t)M2_*4);
  int* rowptr6 = (int*)alloc((size_t)(M3_+1)*4); int* cursor6 = (int*)alloc((size_t)M3_*4);
  int* degi0 = (int*)alloc((size_t)M0_*4);
  int* degi2 = (int*)alloc((size_t)M1_*4);
  int* degi4 = (int*)alloc((size_t)M2_*4);
  int* degi6 = (int*)alloc((size_t)M3_*4);
  float* dinv0 = (float*)alloc((size_t)M0_*4);
  float* dinv2 = (float*)alloc((size_t)M1_*4);
  float* dinv4 = (float*)alloc((size_t)M2_*4);
  float* dinv6 = (float*)alloc((size_t)M3_*4);

  auto NB = [](int total){ return (total+255)/256; };

  // ---- level-0 CSR (shared by layers 1 and 7)
  hipMemsetAsync(degi0, 0, (size_t)M0_*4, stream);
  k_deg0<<<NB(E_),256,0,stream>>>(dst0, degi0);
  k_scan<M0_><<<1,1024,0,stream>>>(degi0, rowptr0, cursor0, dinv0);
  k_place0<<<NB(E_),256,0,stream>>>(src0, dst0, cursor0, col0);

  // ---- layer 1: gcn(x) -> x1 (bufA)
  k_mm<32><<<dim3(M0_/64,1),256,0,stream>>>(x, W1, bufH, M0_, 128, 32);
  k_gather<32><<<NB(M0_*8),256,0,stream>>>(rowptr0, col0, dinv0, bufH, b1, bufA, M0_);

  // ---- pool 1 -> x2 (s1), level-2 CSR via remap2
  k_score<<<NB(M0_),256,0,stream>>>(bufA, p1, score, M0_, 32);
  k_topk<<<B_,1024,0,stream>>>(score, 1024, K1_, idx2, vals);
  hipMemsetAsync(remap2, 0xFF, (size_t)M0_*4, stream);
  k_remap_set<<<NB(M1_),256,0,stream>>>(idx2, remap2, M1_);
  hipMemsetAsync(degi2, 0, (size_t)M1_*4, stream);
  k_deg_rm<<<NB(E_),256,0,stream>>>(src0, dst0, remap2, degi2);
  k_scan<M1_><<<1,1024,0,stream>>>(degi2, rowptr2, cursor2, dinv2);
  k_place_rm<<<NB(E_),256,0,stream>>>(src0, dst0, remap2, cursor2, col2);
  k_pool_gather4<<<NB(M1_*8),256,0,stream>>>(bufA, idx2, vals, s1, M1_, 3, 5);

  // ---- layer 2: gcn(x2) -> x3 (bufB)
  k_mm<64><<<dim3(M1_/64,1),256,0,stream>>>(s1, W2, bufH, M1_, 32, 64);
  k_gather<64><<<NB(M1_*16),256,0,stream>>>(rowptr2, col2, dinv2, bufH, b2, bufB, M1_);

  // ---- pool 2 -> x4 (s1), level-4 CSR via composed rm04
  k_score<<<NB(M1_),256,0,stream>>>(bufB, p2, score, M1_, 64);
  k_topk<<<B_,512,0,stream>>>(score, 512, K2_, idx4, vals);
  hipMemsetAsync(remap4, 0xFF, (size_t)M1_*4, stream);
  k_remap_set<<<NB(M2_),256,0,stream>>>(idx4, remap4, M2_);
  k_compose<<<NB(M0_),256,0,stream>>>(remap2, remap4, rm04, M0_);
  hipMemsetAsync(degi4, 0, (size_t)M2_*4, stream);
  k_deg_rm<<<NB(E_),256,0,stream>>>(src0, dst0, rm04, degi4);
  k_scan<M2_><<<1,1024,0,stream>>>(degi4, rowptr4, cursor4, dinv4);
  k_place_rm<<<NB(E_),256,0,stream>>>(src0, dst0, rm04, cursor4, col4);
  k_pool_gather4<<<NB(M2_*16),256,0,stream>>>(bufB, idx4, vals, s1, M2_, 4, 6);

  // ---- layer 3: gcn(x4) -> x5 (bufC)
  k_mm<128><<<dim3(M2_/64,1),256,0,stream>>>(s1, W3, bufH, M2_, 64, 128);
  k_gather<128><<<NB(M2_*32),256,0,stream>>>(rowptr4, col4, dinv4, bufH, b3, bufC, M2_);

  // ---- pool 3 -> x6 (s1), level-6 CSR via composed rm06
  k_score<<<NB(M2_),256,0,stream>>>(bufC, p3, score, M2_, 128);
  k_topk<<<B_,256,0,stream>>>(score, 256, K3_, idx6, vals);
  hipMemsetAsync(remap6, 0xFF, (size_t)M2_*4, stream);
  k_remap_set<<<NB(M3_),256,0,stream>>>(idx6, remap6, M3_);
  k_compose<<<NB(M0_),256,0,stream>>>(rm04, remap6, rm06, M0_);
  hipMemsetAsync(degi6, 0, (size_t)M3_*4, stream);
  k_deg_rm<<<NB(E_),256,0,stream>>>(src0, dst0, rm06, degi6);
  k_scan<M3_><<<1,1024,0,stream>>>(degi6, rowptr6, cursor6, dinv6);
  k_place_rm<<<NB(E_),256,0,stream>>>(src0, dst0, rm06, cursor6, col6);
  k_pool_gather4<<<NB(M3_*32),256,0,stream>>>(bufC, idx6, vals, s1, M3_, 5, 7);

  // ---- layer 4: gcn(x6) -> x7 (bufD)
  k_mm<128><<<dim3(M3_/64,2),256,0,stream>>>(s1, W4, bufH, M3_, 128, 256);
  k_gather<256><<<NB(M3_*64),256,0,stream>>>(rowptr6, col6, dinv6, bufH, b4, bufD, M3_);

  // ---- unpool+concat -> x8 (cat), layer 5 -> x9 (bufD)
  k_cat<64,32><<<NB(M2_*96),256,0,stream>>>(bufD, remap6, bufC, cat, M2_);
  k_mm<128><<<dim3(M2_/64,1),256,0,stream>>>(cat, W5, bufH, M2_, 384, 128);
  k_gather<128><<<NB(M2_*32),256,0,stream>>>(rowptr4, col4, dinv4, bufH, b5, bufD, M2_);

  // ---- unpool+concat -> x10 (cat), layer 6 -> x11 (bufC)
  k_cat<32,16><<<NB(M1_*48),256,0,stream>>>(bufD, remap4, bufB, cat, M1_);
  k_mm<64><<<dim3(M1_/64,1),256,0,stream>>>(cat, W6, bufH, M1_, 192, 64);
  k_gather<64><<<NB(M1_*16),256,0,stream>>>(rowptr2, col2, dinv2, bufH, b6, bufC, M1_);

  // ---- unpool+concat -> x12 (cat), layer 7 -> x13 (bufA)
  k_cat<16,8><<<NB(M0_*24),256,0,stream>>>(bufC, remap2, bufA, cat, M0_);
  k_mm<32><<<dim3(M0_/64,1),256,0,stream>>>(cat, W7, bufH, M0_, 96, 32);
  k_gather<32><<<NB(M0_*8),256,0,stream>>>(rowptr0, col0, dinv0, bufH, b7, bufA, M0_);

  // ---- head
  k_head<<<B_,256,0,stream>>>(bufA, Wl, Wc, bc, out);

  (void)in_sizes; (void)n_in; (void)out_size; (void)ws_size;
}

// Round 5
// 440.991 us; speedup vs baseline: 3.1088x; 1.1576x over previous
//
#include <hip/hip_runtime.h>
#include <hip/hip_bf16.h>
#include <math.h>

#define B_ 64
#define N_ 1024
#define E_ 524288
#define K1_ 512
#define K2_ 256
#define K3_ 128
#define M0_ 65536
#define M1_ 32768
#define M2_ 16384
#define M3_ 8192

static __device__ __forceinline__ float eluf(float x){ return x > 0.f ? x : expm1f(x); }

// Tiled GEMM: block computes 64 rows x BN cols. K tiled by 32. Writes H only.
template<int BN>
__global__ __launch_bounds__(256) void k_mm(const float* __restrict__ X,
    const float* __restrict__ W, float* __restrict__ H, int M, int K, int N){
  constexpr int TX = BN/4;      // threads across cols (each owns 4 cols)
  constexpr int TY = 256/TX;
  constexpr int RM = 64/TY;     // rows per thread
  __shared__ float Xs[64][36];  // pad 36: conflict-free col reads
  __shared__ float Ws[32][BN];
  const int t = threadIdx.x;
  const int tx = t % TX, ty = t / TX;
  const int m0 = blockIdx.x*64, n0 = blockIdx.y*BN;
  float acc[RM][4];
  #pragma unroll
  for (int r=0;r<RM;++r){acc[r][0]=0.f;acc[r][1]=0.f;acc[r][2]=0.f;acc[r][3]=0.f;}
  for (int k0=0;k0<K;k0+=32){
    #pragma unroll
    for (int r=0;r<2;++r){            // 512 float4s of X tile
      int fi=r*256+t, row=fi>>3, q=fi&7;
      *(float4*)(&Xs[row][q*4]) = *(const float4*)(X + (size_t)(m0+row)*K + k0 + q*4);
    }
    #pragma unroll
    for (int r=0;r<BN/32;++r){        // 8*BN float4s of W tile
      int fi=r*256+t, row=fi/(BN/4), q=fi%(BN/4);
      *(float4*)(&Ws[row][q*4]) = *(const float4*)(W + (size_t)(k0+row)*N + n0 + q*4);
    }
    __syncthreads();
    #pragma unroll
    for (int kk=0;kk<32;++kk){
      float4 wv = *(const float4*)(&Ws[kk][tx*4]);
      #pragma unroll
      for (int r=0;r<RM;++r){
        float xv = Xs[ty*RM+r][kk];
        acc[r][0]=fmaf(xv,wv.x,acc[r][0]);
        acc[r][1]=fmaf(xv,wv.y,acc[r][1]);
        acc[r][2]=fmaf(xv,wv.z,acc[r][2]);
        acc[r][3]=fmaf(xv,wv.w,acc[r][3]);
      }
    }
    __syncthreads();
  }
  #pragma unroll
  for (int r=0;r<RM;++r){
    int m = m0 + ty*RM + r;
    float4 h; h.x=acc[r][0];h.y=acc[r][1];h.z=acc[r][2];h.w=acc[r][3];
    *(float4*)(H + (size_t)m*N + n0 + tx*4) = h;
  }
}

// ---- level-0 CSR build (spread atomics only) ----
__global__ void k_deg0(const int* __restrict__ dst, int* __restrict__ degi){
  int i = blockIdx.x*256+threadIdx.x; if (i>=E_) return;
  atomicAdd(&degi[dst[i]], 1);
}

__global__ void k_place0(const int* __restrict__ src, const int* __restrict__ dst,
                         int* __restrict__ cursor, int* __restrict__ col){
  int i = blockIdx.x*256+threadIdx.x; if (i>=E_) return;
  int p = atomicAdd(&cursor[dst[i]], 1);
  col[p] = src[i];
}

// ---- hierarchical scan over M0 degrees (3 small kernels, all parallel) ----
__global__ __launch_bounds__(256) void k_scanA(const int* __restrict__ degi,
                                               int* __restrict__ bsum){
  __shared__ int ls[256];
  int b = blockIdx.x, t = threadIdx.x;
  ls[t] = degi[b*256+t]; __syncthreads();
  for (int o=128;o>0;o>>=1){ if (t<o) ls[t]+=ls[t+o]; __syncthreads(); }
  if (t==0) bsum[b] = ls[0];
}
__global__ __launch_bounds__(256) void k_scanB(int* __restrict__ bsum){
  __shared__ int ps[256];
  int t = threadIdx.x;
  ps[t] = bsum[t]; __syncthreads();
  for (int o=1;o<256;o<<=1){
    int v = (t>=o) ? ps[t-o] : 0;
    __syncthreads(); ps[t]+=v; __syncthreads();
  }
  bsum[t] = ps[t];   // inclusive
}
__global__ __launch_bounds__(256) void k_scanC(const int* __restrict__ degi,
    const int* __restrict__ bsum, int* __restrict__ rowptr,
    int* __restrict__ cursor, float* __restrict__ dinv){
  __shared__ int ps[256];
  int b = blockIdx.x, t = threadIdx.x;
  int i = b*256+t;
  int d = degi[i];
  ps[t] = d; __syncthreads();
  for (int o=1;o<256;o<<=1){
    int v = (t>=o) ? ps[t-o] : 0;
    __syncthreads(); ps[t]+=v; __syncthreads();
  }
  int off = (b==0 ? 0 : bsum[b-1]) + ps[t] - d;   // exclusive prefix
  rowptr[i] = off; cursor[i] = off;
  dinv[i] = rsqrtf((float)d + 2.f);
  if (i == M0_-1) rowptr[M0_] = off + d;          // == E_
}

// ---- pooled-level degree via rm-filtered level-0 CSR (no atomics, no scan)
__global__ void k_deg_orig(const int* __restrict__ orig, const int* __restrict__ rowptr0,
                           const int* __restrict__ col0, const int* __restrict__ rm,
                           float* __restrict__ dinv, int M){
  int i = blockIdx.x*256+threadIdx.x; if (i>=M) return;
  int o = orig[i];
  int beg = rowptr0[o], end = rowptr0[o+1];
  int d = 0;
  for (int j=beg;j<end;++j) d += (rm[col0[j]] >= 0) ? 1 : 0;
  dinv[i] = rsqrtf((float)d + 2.f);
}

// origL[i] = prevOrig[idxL[i]]
__global__ void k_compose_idx(const int* __restrict__ prevOrig, const int* __restrict__ idxL,
                              int* __restrict__ origL, int n){
  int i = blockIdx.x*256+threadIdx.x; if (i<n) origL[i] = prevOrig[idxL[i]];
}

// ---- level-0 GCN aggregation (identity remap)
template<int F>
__global__ __launch_bounds__(256) void k_gather(const int* __restrict__ rowptr,
    const int* __restrict__ col, const float* __restrict__ dinv,
    const float* __restrict__ H, const float* __restrict__ bias,
    float* __restrict__ OUT, int M){
  constexpr int FQ = F/4;
  int i = blockIdx.x*256+threadIdx.x;
  if (i >= M*FQ) return;
  int n = i/FQ, q = i - (i/FQ)*FQ;
  int beg = rowptr[n], end = rowptr[n+1];
  float4 acc; acc.x=0.f;acc.y=0.f;acc.z=0.f;acc.w=0.f;
  for (int j=beg;j<end;++j){
    int s = col[j];
    float c = dinv[s];
    float4 h = *(const float4*)(H + (size_t)s*F + q*4);
    acc.x=fmaf(c,h.x,acc.x); acc.y=fmaf(c,h.y,acc.y);
    acc.z=fmaf(c,h.z,acc.z); acc.w=fmaf(c,h.w,acc.w);
  }
  float dn = dinv[n];
  float sc = 2.f*dn*dn;
  float4 hn = *(const float4*)(H + (size_t)n*F + q*4);
  float4 bv = *(const float4*)(bias + q*4);
  float4 o;
  o.x = eluf(fmaf(sc,hn.x,fmaf(dn,acc.x,bv.x)));
  o.y = eluf(fmaf(sc,hn.y,fmaf(dn,acc.y,bv.y)));
  o.z = eluf(fmaf(sc,hn.z,fmaf(dn,acc.z,bv.z)));
  o.w = eluf(fmaf(sc,hn.w,fmaf(dn,acc.w,bv.w)));
  *(float4*)(OUT + (size_t)n*F + q*4) = o;
}

// ---- pooled-level GCN aggregation through rm filter on level-0 CSR
template<int F>
__global__ __launch_bounds__(256) void k_gather_rm(const int* __restrict__ orig,
    const int* __restrict__ rowptr0, const int* __restrict__ col0,
    const int* __restrict__ rm, const float* __restrict__ dinv,
    const float* __restrict__ H, const float* __restrict__ bias,
    float* __restrict__ OUT, int M){
  constexpr int FQ = F/4;
  int i = blockIdx.x*256+threadIdx.x;
  if (i >= M*FQ) return;
  int n = i/FQ, q = i - (i/FQ)*FQ;
  int o = orig[n];
  int beg = rowptr0[o], end = rowptr0[o+1];
  float4 acc; acc.x=0.f;acc.y=0.f;acc.z=0.f;acc.w=0.f;
  for (int j=beg;j<end;++j){
    int s = rm[col0[j]];
    if (s >= 0){
      float c = dinv[s];
      float4 h = *(const float4*)(H + (size_t)s*F + q*4);
      acc.x=fmaf(c,h.x,acc.x); acc.y=fmaf(c,h.y,acc.y);
      acc.z=fmaf(c,h.z,acc.z); acc.w=fmaf(c,h.w,acc.w);
    }
  }
  float dn = dinv[n];
  float sc = 2.f*dn*dn;
  float4 hn = *(const float4*)(H + (size_t)n*F + q*4);
  float4 bv = *(const float4*)(bias + q*4);
  float4 ov;
  ov.x = eluf(fmaf(sc,hn.x,fmaf(dn,acc.x,bv.x)));
  ov.y = eluf(fmaf(sc,hn.y,fmaf(dn,acc.y,bv.y)));
  ov.z = eluf(fmaf(sc,hn.z,fmaf(dn,acc.z,bv.z)));
  ov.w = eluf(fmaf(sc,hn.w,fmaf(dn,acc.w,bv.w)));
  *(float4*)(OUT + (size_t)n*F + q*4) = ov;
}

__global__ void k_score(const float* __restrict__ X, const float* __restrict__ p,
                        float* __restrict__ s, int M, int F){
  int i = blockIdx.x*256+threadIdx.x; if (i>=M) return;
  float dot=0.f, n2=0.f;
  const float* xr = X + (size_t)i*F;
  for (int f=0; f<F; ++f){ dot = fmaf(xr[f], p[f], dot); n2 = fmaf(p[f],p[f],n2); }
  s[i] = tanhf(dot / sqrtf(n2));
}

// block g sorts its npg scores descending (tie: lower index first), writes top-K
__global__ void k_topk(const float* __restrict__ score, int npg, int K,
                       int* __restrict__ perm, float* __restrict__ vals){
  __shared__ float ss[1024]; __shared__ int si[1024];
  int g = blockIdx.x, tid = threadIdx.x;
  ss[tid] = score[g*npg + tid]; si[tid] = tid;
  __syncthreads();
  for (int k=2;k<=npg;k<<=1){
    for (int j=k>>1;j>0;j>>=1){
      int ixj = tid ^ j;
      if (ixj > tid){
        float s1=ss[tid], s2=ss[ixj]; int i1=si[tid], i2=si[ixj];
        bool aAfterB = (s1 < s2) || (s1==s2 && i1 > i2);
        bool sw = ((tid & k)==0) ? aAfterB : !aAfterB;
        if (sw){ ss[tid]=s2; si[tid]=i2; ss[ixj]=s1; si[ixj]=i1; }
      }
      __syncthreads();
    }
  }
  if (tid < K){ perm[g*K+tid] = g*npg + si[tid]; vals[g*K+tid] = ss[tid]; }
}

__global__ void k_remap_set(const int* __restrict__ perm, int* __restrict__ remap, int n){
  int i = blockIdx.x*256+threadIdx.x; if (i<n) remap[perm[i]] = i;
}

// Xout[i,:] = elu(Xin[perm[i],:] * vals[i]); F = 1<<fsh
__global__ void k_pool_gather4(const float* __restrict__ Xin, const int* __restrict__ perm,
                               const float* __restrict__ vals, float* __restrict__ Xout,
                               int Mout, int fqsh, int fsh){
  int total = Mout<<fqsh;
  int i = blockIdx.x*256+threadIdx.x; if (i>=total) return;
  int m = i>>fqsh, q = i&((1<<fqsh)-1);
  float v = vals[m];
  float4 h = *(const float4*)(Xin + ((size_t)perm[m]<<fsh) + q*4);
  float4 o; o.x=eluf(h.x*v); o.y=eluf(h.y*v); o.z=eluf(h.z*v); o.w=eluf(h.w*v);
  *(float4*)(Xout + ((size_t)m<<fsh) + q*4) = o;
}

// concat: cat[r,0:WD] = (rm_next[orig_cur[r]]>=0 ? elu(Xd[..]) : 0), cat[r,WD:]=elu(Xs[r])
template<int WD4,int WS4>
__global__ void k_cat(const float* __restrict__ Xd, const int* __restrict__ orig,
                      const int* __restrict__ rm, const float* __restrict__ Xs,
                      float* __restrict__ cat, int rows){
  constexpr int W4 = WD4+WS4;
  int total = rows*W4;
  int i = blockIdx.x*256+threadIdx.x; if (i>=total) return;
  int r = i/W4, c = i - r*W4;
  float4 v;
  if (c < WD4){
    int o = orig ? orig[r] : r;
    int j = rm[o];
    if (j>=0) v = *(const float4*)(Xd + (size_t)j*(WD4*4) + c*4);
    else { v.x=0.f;v.y=0.f;v.z=0.f;v.w=0.f; }
  } else {
    v = *(const float4*)(Xs + (size_t)r*(WS4*4) + (c-WD4)*4);
  }
  float4 o4; o4.x=eluf(v.x); o4.y=eluf(v.y); o4.z=eluf(v.z); o4.w=eluf(v.w);
  *(float4*)(cat + (size_t)i*4) = o4;
}

// per-graph global max/mean pool over (1024,32), then MLP head + log_softmax
__global__ void k_head(const float* __restrict__ x13, const float* __restrict__ Wl,
                       const float* __restrict__ Wc, const float* __restrict__ bc,
                       float* __restrict__ out){
  __shared__ float smax[256], ssum[256];
  __shared__ float gv[64], g2[64], logit[10];
  int g = blockIdx.x, t = threadIdx.x;
  int f = t & 31, r0 = t >> 5;
  float mx = -3.4e38f, sm = 0.f;
  const float* base = x13 + (size_t)g*N_*32;
  for (int r=r0; r<N_; r+=8){ float v = base[r*32+f]; mx = fmaxf(mx,v); sm += v; }
  smax[t]=mx; ssum[t]=sm; __syncthreads();
  if (t<128){ smax[t]=fmaxf(smax[t],smax[t+128]); ssum[t]+=ssum[t+128]; } __syncthreads();
  if (t<64){ smax[t]=fmaxf(smax[t],smax[t+64]); ssum[t]+=ssum[t+64]; } __syncthreads();
  if (t<32){
    float m2 = fmaxf(smax[t],smax[t+32]); float s2 = ssum[t]+ssum[t+32];
    gv[t] = eluf(m2); gv[32+t] = eluf(s2 * (1.f/N_));
  }
  __syncthreads();
  if (t<64){
    float acc=0.f;
    #pragma unroll
    for (int i2=0;i2<64;++i2) acc = fmaf(gv[i2], Wl[i2*64+t], acc);
    g2[t] = eluf(acc);
  }
  __syncthreads();
  if (t<10){
    float acc = bc[t];
    #pragma unroll
    for (int j=0;j<64;++j) acc = fmaf(g2[j], Wc[j*10+t], acc);
    logit[t] = acc;
  }
  __syncthreads();
  if (t==0){
    float m=-3.4e38f; for (int c=0;c<10;++c) m=fmaxf(m,logit[c]);
    float s=0.f; for (int c=0;c<10;++c) s += expf(logit[c]-m);
    float lse = m + logf(s);
    for (int c=0;c<10;++c) out[g*10+c] = logit[c]-lse;
  }
}

extern "C" void kernel_launch(void* const* d_in, const int* in_sizes, int n_in,
                              void* d_out, int out_size, void* d_ws, size_t ws_size,
                              hipStream_t stream){
  const float* x  = (const float*)d_in[0];
  const float* W1 = (const float*)d_in[1];
  const float* b1 = (const float*)d_in[2];
  const float* p1 = (const float*)d_in[3];
  const float* W2 = (const float*)d_in[4];
  const float* b2 = (const float*)d_in[5];
  const float* p2 = (const float*)d_in[6];
  const float* W3 = (const float*)d_in[7];
  const float* b3 = (const float*)d_in[8];
  const float* p3 = (const float*)d_in[9];
  const float* W4 = (const float*)d_in[10];
  const float* b4 = (const float*)d_in[11];
  const float* W5 = (const float*)d_in[12];
  const float* b5 = (const float*)d_in[13];
  const float* W6 = (const float*)d_in[14];
  const float* b6 = (const float*)d_in[15];
  const float* W7 = (const float*)d_in[16];
  const float* b7 = (const float*)d_in[17];
  const float* Wl = (const float*)d_in[18];
  const float* Wc = (const float*)d_in[19];
  const float* bc = (const float*)d_in[20];
  const int* src0 = (const int*)d_in[21];
  const int* dst0 = (const int*)d_in[22];
  float* out = (float*)d_out;

  char* wsp = (char*)d_ws;
  size_t off = 0;
  auto alloc = [&](size_t bytes)->char*{
    char* p = wsp + off;
    off += (bytes + 255) & ~(size_t)255;
    return p;
  };
  float* bufA = (float*)alloc((size_t)2097152*4);   // x1 / x13
  float* bufB = (float*)alloc((size_t)2097152*4);   // x3
  float* bufC = (float*)alloc((size_t)2097152*4);   // x5 / x11
  float* bufD = (float*)alloc((size_t)2097152*4);   // x7 / x9
  float* bufH = (float*)alloc((size_t)2097152*4);   // pre-norm H
  float* cat  = (float*)alloc((size_t)6291456*4);   // concat buffer
  float* s1   = (float*)alloc((size_t)1048576*4);   // x2/x4/x6
  float* score= (float*)alloc((size_t)65536*4);
  float* vals = (float*)alloc((size_t)32768*4);
  int* idx2 = (int*)alloc((size_t)M1_*4);   // level2 -> level0 (orig2)
  int* idx4 = (int*)alloc((size_t)M2_*4);   // level4 -> level2
  int* idx6 = (int*)alloc((size_t)M3_*4);   // level6 -> level4
  int* orig4 = (int*)alloc((size_t)M2_*4);  // level4 -> level0
  int* orig6 = (int*)alloc((size_t)M3_*4);  // level6 -> level0
  int* rm02 = (int*)alloc((size_t)M0_*4);   // level0 -> level2 id or -1
  int* rm04 = (int*)alloc((size_t)M0_*4);
  int* rm06 = (int*)alloc((size_t)M0_*4);
  int* col0 = (int*)alloc((size_t)E_*4);
  int* rowptr0 = (int*)alloc((size_t)(M0_+1)*4);
  int* cursor0 = (int*)alloc((size_t)M0_*4);
  int* degi0 = (int*)alloc((size_t)M0_*4);
  int* bsum  = (int*)alloc((size_t)256*4);
  float* dinv0 = (float*)alloc((size_t)M0_*4);
  float* dinv2 = (float*)alloc((size_t)M1_*4);
  float* dinv4 = (float*)alloc((size_t)M2_*4);
  float* dinv6 = (float*)alloc((size_t)M3_*4);

  auto NB = [](int total){ return (total+255)/256; };

  // ---- level-0 CSR (shared by layers 1 and 7)
  hipMemsetAsync(degi0, 0, (size_t)M0_*4, stream);
  k_deg0<<<NB(E_),256,0,stream>>>(dst0, degi0);
  k_scanA<<<256,256,0,stream>>>(degi0, bsum);
  k_scanB<<<1,256,0,stream>>>(bsum);
  k_scanC<<<256,256,0,stream>>>(degi0, bsum, rowptr0, cursor0, dinv0);
  k_place0<<<NB(E_),256,0,stream>>>(src0, dst0, cursor0, col0);

  // ---- layer 1: gcn(x) -> x1 (bufA)
  k_mm<32><<<dim3(M0_/64,1),256,0,stream>>>(x, W1, bufH, M0_, 128, 32);
  k_gather<32><<<NB(M0_*8),256,0,stream>>>(rowptr0, col0, dinv0, bufH, b1, bufA, M0_);

  // ---- pool 1 -> x2 (s1); rm02/dinv2
  k_score<<<NB(M0_),256,0,stream>>>(bufA, p1, score, M0_, 32);
  k_topk<<<B_,1024,0,stream>>>(score, 1024, K1_, idx2, vals);
  hipMemsetAsync(rm02, 0xFF, (size_t)M0_*4, stream);
  k_remap_set<<<NB(M1_),256,0,stream>>>(idx2, rm02, M1_);
  k_deg_orig<<<NB(M1_),256,0,stream>>>(idx2, rowptr0, col0, rm02, dinv2, M1_);
  k_pool_gather4<<<NB(M1_*8),256,0,stream>>>(bufA, idx2, vals, s1, M1_, 3, 5);

  // ---- layer 2: gcn(x2) -> x3 (bufB)
  k_mm<64><<<dim3(M1_/64,1),256,0,stream>>>(s1, W2, bufH, M1_, 32, 64);
  k_gather_rm<64><<<NB(M1_*16),256,0,stream>>>(idx2, rowptr0, col0, rm02, dinv2, bufH, b2, bufB, M1_);

  // ---- pool 2 -> x4 (s1); orig4/rm04/dinv4
  k_score<<<NB(M1_),256,0,stream>>>(bufB, p2, score, M1_, 64);
  k_topk<<<B_,512,0,stream>>>(score, 512, K2_, idx4, vals);
  k_compose_idx<<<NB(M2_),256,0,stream>>>(idx2, idx4, orig4, M2_);
  hipMemsetAsync(rm04, 0xFF, (size_t)M0_*4, stream);
  k_remap_set<<<NB(M2_),256,0,stream>>>(orig4, rm04, M2_);
  k_deg_orig<<<NB(M2_),256,0,stream>>>(orig4, rowptr0, col0, rm04, dinv4, M2_);
  k_pool_gather4<<<NB(M2_*16),256,0,stream>>>(bufB, idx4, vals, s1, M2_, 4, 6);

  // ---- layer 3: gcn(x4) -> x5 (bufC)
  k_mm<128><<<dim3(M2_/64,1),256,0,stream>>>(s1, W3, bufH, M2_, 64, 128);
  k_gather_rm<128><<<NB(M2_*32),256,0,stream>>>(orig4, rowptr0, col0, rm04, dinv4, bufH, b3, bufC, M2_);

  // ---- pool 3 -> x6 (s1); orig6/rm06/dinv6
  k_score<<<NB(M2_),256,0,stream>>>(bufC, p3, score, M2_, 128);
  k_topk<<<B_,256,0,stream>>>(score, 256, K3_, idx6, vals);
  k_compose_idx<<<NB(M3_),256,0,stream>>>(orig4, idx6, orig6, M3_);
  hipMemsetAsync(rm06, 0xFF, (size_t)M0_*4, stream);
  k_remap_set<<<NB(M3_),256,0,stream>>>(orig6, rm06, M3_);
  k_deg_orig<<<NB(M3_),256,0,stream>>>(orig6, rowptr0, col0, rm06, dinv6, M3_);
  k_pool_gather4<<<NB(M3_*32),256,0,stream>>>(bufC, idx6, vals, s1, M3_, 5, 7);

  // ---- layer 4: gcn(x6) -> x7 (bufD)
  k_mm<128><<<dim3(M3_/64,2),256,0,stream>>>(s1, W4, bufH, M3_, 128, 256);
  k_gather_rm<256><<<NB(M3_*64),256,0,stream>>>(orig6, rowptr0, col0, rm06, dinv6, bufH, b4, bufD, M3_);

  // ---- unpool+concat -> x8 (cat), layer 5 -> x9 (bufD)  [level 4]
  k_cat<64,32><<<NB(M2_*96),256,0,stream>>>(bufD, orig4, rm06, bufC, cat, M2_);
  k_mm<128><<<dim3(M2_/64,1),256,0,stream>>>(cat, W5, bufH, M2_, 384, 128);
  k_gather_rm<128><<<NB(M2_*32),256,0,stream>>>(orig4, rowptr0, col0, rm04, dinv4, bufH, b5, bufD, M2_);

  // ---- unpool+concat -> x10 (cat), layer 6 -> x11 (bufC)  [level 2]
  k_cat<32,16><<<NB(M1_*48),256,0,stream>>>(bufD, idx2, rm04, bufB, cat, M1_);
  k_mm<64><<<dim3(M1_/64,1),256,0,stream>>>(cat, W6, bufH, M1_, 192, 64);
  k_gather_rm<64><<<NB(M1_*16),256,0,stream>>>(idx2, rowptr0, col0, rm02, dinv2, bufH, b6, bufC, M1_);

  // ---- unpool+concat -> x12 (cat), layer 7 -> x13 (bufA)  [level 0]
  k_cat<16,8><<<NB(M0_*24),256,0,stream>>>(bufC, nullptr, rm02, bufA, cat, M0_);
  k_mm<32><<<dim3(M0_/64,1),256,0,stream>>>(cat, W7, bufH, M0_, 96, 32);
  k_gather<32><<<NB(M0_*8),256,0,stream>>>(rowptr0, col0, dinv0, bufH, b7, bufA, M0_);

  // ---- head
  k_head<<<B_,256,0,stream>>>(bufA, Wl, Wc, bc, out);

  (void)in_sizes; (void)n_in; (void)out_size; (void)ws_size;
}

// Round 6
// 399.947 us; speedup vs baseline: 3.4279x; 1.1026x over previous
//
#include <hip/hip_runtime.h>
#include <hip/hip_bf16.h>
#include <math.h>

#define B_ 64
#define N_ 1024
#define E_ 524288
#define K1_ 512
#define K2_ 256
#define K3_ 128
#define M0_ 65536
#define M1_ 32768
#define M2_ 16384
#define M3_ 8192

static __device__ __forceinline__ float eluf(float x){ return x > 0.f ? x : expm1f(x); }
static __device__ __forceinline__ float4 elu4(float4 v){
  float4 o; o.x=eluf(v.x); o.y=eluf(v.y); o.z=eluf(v.z); o.w=eluf(v.w); return o;
}

// Tiled GEMM, BM x BN block, 256 threads, 4-col x RM-row micro-tile.
// MODE 0: H = X @ W                  (X raw, width K)
// MODE 1: H = elu(X[perm[m]]*vals[m]) @ W      (fused top-k pool gather)
// MODE 2: H = elu(concat(Xd via rm/orig, Xs)) @ W  (fused unpool+concat; left
//          width WD4*4 from Xd[rm[orig[m]]], right from Xs row m)
template<int BM,int BN,int MODE>
__global__ __launch_bounds__(256) void k_mm(const float* __restrict__ X,
    const float* __restrict__ W, float* __restrict__ H, int M, int K, int N,
    const int* __restrict__ perm, const float* __restrict__ vals,
    const float* __restrict__ Xd, const int* __restrict__ orig,
    const int* __restrict__ rm, int WD4){
  constexpr int TX = BN/4;
  constexpr int TY = 256/TX;
  constexpr int RM = BM/TY;
  __shared__ float Xs[BM][36];   // pad 36: 16B-aligned rows; broadcast reads 2-way max
  __shared__ float Ws[32][BN];
  const int t = threadIdx.x;
  const int tx = t % TX, ty = t / TX;
  const int m0 = blockIdx.x*BM, n0 = blockIdx.y*BN;
  float acc[RM][4];
  #pragma unroll
  for (int r=0;r<RM;++r){acc[r][0]=0.f;acc[r][1]=0.f;acc[r][2]=0.f;acc[r][3]=0.f;}
  for (int k0=0;k0<K;k0+=32){
    #pragma unroll
    for (int r=0;r<BM/32;++r){           // X tile: BM*8 float4s
      int fi=r*256+t, row=fi>>3, q=fi&7;
      int m = m0+row;
      int c4 = (k0>>2)+q;
      float4 v;
      if (MODE==0){
        v = *(const float4*)(X + (size_t)m*K + (c4<<2));
      } else if (MODE==1){
        int pm = perm[m]; float vv = vals[m];
        float4 h = *(const float4*)(X + (size_t)pm*K + (c4<<2));
        v.x=eluf(h.x*vv); v.y=eluf(h.y*vv); v.z=eluf(h.z*vv); v.w=eluf(h.w*vv);
      } else {
        if (c4 < WD4){
          int o = orig ? orig[m] : m;
          int j = rm[o];
          if (j>=0) v = elu4(*(const float4*)(Xd + ((size_t)j*WD4 + c4)*4));
          else { v.x=0.f;v.y=0.f;v.z=0.f;v.w=0.f; }
        } else {
          int ws4 = (K>>2) - WD4;
          v = elu4(*(const float4*)(X + ((size_t)m*ws4 + (c4-WD4))*4));
        }
      }
      *(float4*)(&Xs[row][q*4]) = v;
    }
    #pragma unroll
    for (int r=0;r<BN/32;++r){           // W tile: 8*BN float4s
      int fi=r*256+t, row=fi/(BN/4), q=fi%(BN/4);
      *(float4*)(&Ws[row][q*4]) = *(const float4*)(W + (size_t)(k0+row)*N + n0 + q*4);
    }
    __syncthreads();
    #pragma unroll
    for (int kk=0;kk<32;++kk){
      float4 wv = *(const float4*)(&Ws[kk][tx*4]);
      #pragma unroll
      for (int r=0;r<RM;++r){
        float xv = Xs[ty*RM+r][kk];
        acc[r][0]=fmaf(xv,wv.x,acc[r][0]);
        acc[r][1]=fmaf(xv,wv.y,acc[r][1]);
        acc[r][2]=fmaf(xv,wv.z,acc[r][2]);
        acc[r][3]=fmaf(xv,wv.w,acc[r][3]);
      }
    }
    __syncthreads();
  }
  #pragma unroll
  for (int r=0;r<RM;++r){
    int m = m0 + ty*RM + r;
    float4 h; h.x=acc[r][0];h.y=acc[r][1];h.z=acc[r][2];h.w=acc[r][3];
    *(float4*)(H + (size_t)m*N + n0 + tx*4) = h;
  }
}

// ---- level-0 CSR build (spread atomics only) ----
__global__ void k_deg0(const int* __restrict__ dst, int* __restrict__ degi){
  int i = blockIdx.x*256+threadIdx.x; if (i>=E_) return;
  atomicAdd(&degi[dst[i]], 1);
}
__global__ void k_place0(const int* __restrict__ src, const int* __restrict__ dst,
                         int* __restrict__ cursor, int* __restrict__ col){
  int i = blockIdx.x*256+threadIdx.x; if (i>=E_) return;
  int p = atomicAdd(&cursor[dst[i]], 1);
  col[p] = src[i];
}

// ---- hierarchical scan over M0 degrees ----
__global__ __launch_bounds__(256) void k_scanA(const int* __restrict__ degi,
                                               int* __restrict__ bsum){
  __shared__ int ls[256];
  int b = blockIdx.x, t = threadIdx.x;
  ls[t] = degi[b*256+t]; __syncthreads();
  for (int o=128;o>0;o>>=1){ if (t<o) ls[t]+=ls[t+o]; __syncthreads(); }
  if (t==0) bsum[b] = ls[0];
}
__global__ __launch_bounds__(256) void k_scanB(int* __restrict__ bsum){
  __shared__ int ps[256];
  int t = threadIdx.x;
  ps[t] = bsum[t]; __syncthreads();
  for (int o=1;o<256;o<<=1){
    int v = (t>=o) ? ps[t-o] : 0;
    __syncthreads(); ps[t]+=v; __syncthreads();
  }
  bsum[t] = ps[t];
}
__global__ __launch_bounds__(256) void k_scanC(const int* __restrict__ degi,
    const int* __restrict__ bsum, int* __restrict__ rowptr,
    int* __restrict__ cursor, float* __restrict__ dinv){
  __shared__ int ps[256];
  int b = blockIdx.x, t = threadIdx.x;
  int i = b*256+t;
  int d = degi[i];
  ps[t] = d; __syncthreads();
  for (int o=1;o<256;o<<=1){
    int v = (t>=o) ? ps[t-o] : 0;
    __syncthreads(); ps[t]+=v; __syncthreads();
  }
  int off = (b==0 ? 0 : bsum[b-1]) + ps[t] - d;
  rowptr[i] = off; cursor[i] = off;
  dinv[i] = rsqrtf((float)d + 2.f);
  if (i == M0_-1) rowptr[M0_] = off + d;
}

// pooled-level degree via rm-filtered level-0 CSR
__global__ void k_deg_orig(const int* __restrict__ orig, const int* __restrict__ rowptr0,
                           const int* __restrict__ col0, const int* __restrict__ rm,
                           float* __restrict__ dinv, int M){
  int i = blockIdx.x*256+threadIdx.x; if (i>=M) return;
  int o = orig[i];
  int beg = rowptr0[o], end = rowptr0[o+1];
  int d = 0;
  for (int j=beg;j<end;++j) d += (rm[col0[j]] >= 0) ? 1 : 0;
  dinv[i] = rsqrtf((float)d + 2.f);
}

__global__ void k_compose_idx(const int* __restrict__ prevOrig, const int* __restrict__ idxL,
                              int* __restrict__ origL, int n){
  int i = blockIdx.x*256+threadIdx.x; if (i<n) origL[i] = prevOrig[idxL[i]];
}

// ---- level-0 GCN aggregation; optional fused pool-score output
template<int F, bool SCORE>
__global__ __launch_bounds__(256) void k_gather(const int* __restrict__ rowptr,
    const int* __restrict__ col, const float* __restrict__ dinv,
    const float* __restrict__ H, const float* __restrict__ bias,
    float* __restrict__ OUT, int M,
    const float* __restrict__ p, float* __restrict__ score){
  constexpr int FQ = F/4;
  int i = blockIdx.x*256+threadIdx.x;
  if (i >= M*FQ) return;
  int n = i/FQ, q = i - (i/FQ)*FQ;
  int beg = rowptr[n], end = rowptr[n+1];
  float4 acc; acc.x=0.f;acc.y=0.f;acc.z=0.f;acc.w=0.f;
  for (int j=beg;j<end;++j){
    int s = col[j];
    float c = dinv[s];
    float4 h = *(const float4*)(H + (size_t)s*F + q*4);
    acc.x=fmaf(c,h.x,acc.x); acc.y=fmaf(c,h.y,acc.y);
    acc.z=fmaf(c,h.z,acc.z); acc.w=fmaf(c,h.w,acc.w);
  }
  float dn = dinv[n];
  float sc = 2.f*dn*dn;
  float4 hn = *(const float4*)(H + (size_t)n*F + q*4);
  float4 bv = *(const float4*)(bias + q*4);
  float4 o;
  o.x = eluf(fmaf(sc,hn.x,fmaf(dn,acc.x,bv.x)));
  o.y = eluf(fmaf(sc,hn.y,fmaf(dn,acc.y,bv.y)));
  o.z = eluf(fmaf(sc,hn.z,fmaf(dn,acc.z,bv.z)));
  o.w = eluf(fmaf(sc,hn.w,fmaf(dn,acc.w,bv.w)));
  *(float4*)(OUT + (size_t)n*F + q*4) = o;
  if (SCORE){
    float4 pv = *(const float4*)(p + q*4);
    float dot = o.x*pv.x + o.y*pv.y + o.z*pv.z + o.w*pv.w;
    float n2  = pv.x*pv.x + pv.y*pv.y + pv.z*pv.z + pv.w*pv.w;
    #pragma unroll
    for (int mk=FQ>>1; mk>0; mk>>=1){
      dot += __shfl_xor(dot, mk);
      n2  += __shfl_xor(n2,  mk);
    }
    if (q==0) score[n] = tanhf(dot * rsqrtf(n2));
  }
}

// ---- pooled-level GCN aggregation through rm filter; optional fused score
template<int F, bool SCORE>
__global__ __launch_bounds__(256) void k_gather_rm(const int* __restrict__ orig,
    const int* __restrict__ rowptr0, const int* __restrict__ col0,
    const int* __restrict__ rm, const float* __restrict__ dinv,
    const float* __restrict__ H, const float* __restrict__ bias,
    float* __restrict__ OUT, int M,
    const float* __restrict__ p, float* __restrict__ score){
  constexpr int FQ = F/4;
  int i = blockIdx.x*256+threadIdx.x;
  if (i >= M*FQ) return;
  int n = i/FQ, q = i - (i/FQ)*FQ;
  int o = orig[n];
  int beg = rowptr0[o], end = rowptr0[o+1];
  float4 acc; acc.x=0.f;acc.y=0.f;acc.z=0.f;acc.w=0.f;
  for (int j=beg;j<end;++j){
    int s = rm[col0[j]];
    if (s >= 0){
      float c = dinv[s];
      float4 h = *(const float4*)(H + (size_t)s*F + q*4);
      acc.x=fmaf(c,h.x,acc.x); acc.y=fmaf(c,h.y,acc.y);
      acc.z=fmaf(c,h.z,acc.z); acc.w=fmaf(c,h.w,acc.w);
    }
  }
  float dn = dinv[n];
  float sc = 2.f*dn*dn;
  float4 hn = *(const float4*)(H + (size_t)n*F + q*4);
  float4 bv = *(const float4*)(bias + q*4);
  float4 ov;
  ov.x = eluf(fmaf(sc,hn.x,fmaf(dn,acc.x,bv.x)));
  ov.y = eluf(fmaf(sc,hn.y,fmaf(dn,acc.y,bv.y)));
  ov.z = eluf(fmaf(sc,hn.z,fmaf(dn,acc.z,bv.z)));
  ov.w = eluf(fmaf(sc,hn.w,fmaf(dn,acc.w,bv.w)));
  *(float4*)(OUT + (size_t)n*F + q*4) = ov;
  if (SCORE){
    float4 pv = *(const float4*)(p + q*4);
    float dot = ov.x*pv.x + ov.y*pv.y + ov.z*pv.z + ov.w*pv.w;
    float n2  = pv.x*pv.x + pv.y*pv.y + pv.z*pv.z + pv.w*pv.w;
    #pragma unroll
    for (int mk=FQ>>1; mk>0; mk>>=1){
      dot += __shfl_xor(dot, mk);
      n2  += __shfl_xor(n2,  mk);
    }
    if (q==0) score[n] = tanhf(dot * rsqrtf(n2));
  }
}

// block g sorts its npg scores descending (tie: lower index first), writes top-K
__global__ void k_topk(const float* __restrict__ score, int npg, int K,
                       int* __restrict__ perm, float* __restrict__ vals){
  __shared__ float ss[1024]; __shared__ int si[1024];
  int g = blockIdx.x, tid = threadIdx.x;
  ss[tid] = score[g*npg + tid]; si[tid] = tid;
  __syncthreads();
  for (int k=2;k<=npg;k<<=1){
    for (int j=k>>1;j>0;j>>=1){
      int ixj = tid ^ j;
      if (ixj > tid){
        float s1=ss[tid], s2=ss[ixj]; int i1=si[tid], i2=si[ixj];
        bool aAfterB = (s1 < s2) || (s1==s2 && i1 > i2);
        bool sw = ((tid & k)==0) ? aAfterB : !aAfterB;
        if (sw){ ss[tid]=s2; si[tid]=i2; ss[ixj]=s1; si[ixj]=i1; }
      }
      __syncthreads();
    }
  }
  if (tid < K){ perm[g*K+tid] = g*npg + si[tid]; vals[g*K+tid] = ss[tid]; }
}

__global__ void k_remap_set(const int* __restrict__ perm, int* __restrict__ remap, int n){
  int i = blockIdx.x*256+threadIdx.x; if (i<n) remap[perm[i]] = i;
}

// per-graph global max/mean pool over (1024,32), then MLP head + log_softmax
__global__ void k_head(const float* __restrict__ x13, const float* __restrict__ Wl,
                       const float* __restrict__ Wc, const float* __restrict__ bc,
                       float* __restrict__ out){
  __shared__ float smax[256], ssum[256];
  __shared__ float gv[64], g2[64], logit[10];
  int g = blockIdx.x, t = threadIdx.x;
  int f = t & 31, r0 = t >> 5;
  float mx = -3.4e38f, sm = 0.f;
  const float* base = x13 + (size_t)g*N_*32;
  for (int r=r0; r<N_; r+=8){ float v = base[r*32+f]; mx = fmaxf(mx,v); sm += v; }
  smax[t]=mx; ssum[t]=sm; __syncthreads();
  if (t<128){ smax[t]=fmaxf(smax[t],smax[t+128]); ssum[t]+=ssum[t+128]; } __syncthreads();
  if (t<64){ smax[t]=fmaxf(smax[t],smax[t+64]); ssum[t]+=ssum[t+64]; } __syncthreads();
  if (t<32){
    float m2 = fmaxf(smax[t],smax[t+32]); float s2 = ssum[t]+ssum[t+32];
    gv[t] = eluf(m2); gv[32+t] = eluf(s2 * (1.f/N_));
  }
  __syncthreads();
  if (t<64){
    float acc=0.f;
    #pragma unroll
    for (int i2=0;i2<64;++i2) acc = fmaf(gv[i2], Wl[i2*64+t], acc);
    g2[t] = eluf(acc);
  }
  __syncthreads();
  if (t<10){
    float acc = bc[t];
    #pragma unroll
    for (int j=0;j<64;++j) acc = fmaf(g2[j], Wc[j*10+t], acc);
    logit[t] = acc;
  }
  __syncthreads();
  if (t==0){
    float m=-3.4e38f; for (int c=0;c<10;++c) m=fmaxf(m,logit[c]);
    float s=0.f; for (int c=0;c<10;++c) s += expf(logit[c]-m);
    float lse = m + logf(s);
    for (int c=0;c<10;++c) out[g*10+c] = logit[c]-lse;
  }
}

extern "C" void kernel_launch(void* const* d_in, const int* in_sizes, int n_in,
                              void* d_out, int out_size, void* d_ws, size_t ws_size,
                              hipStream_t stream){
  const float* x  = (const float*)d_in[0];
  const float* W1 = (const float*)d_in[1];
  const float* b1 = (const float*)d_in[2];
  const float* p1 = (const float*)d_in[3];
  const float* W2 = (const float*)d_in[4];
  const float* b2 = (const float*)d_in[5];
  const float* p2 = (const float*)d_in[6];
  const float* W3 = (const float*)d_in[7];
  const float* b3 = (const float*)d_in[8];
  const float* p3 = (const float*)d_in[9];
  const float* W4 = (const float*)d_in[10];
  const float* b4 = (const float*)d_in[11];
  const float* W5 = (const float*)d_in[12];
  const float* b5 = (const float*)d_in[13];
  const float* W6 = (const float*)d_in[14];
  const float* b6 = (const float*)d_in[15];
  const float* W7 = (const float*)d_in[16];
  const float* b7 = (const float*)d_in[17];
  const float* Wl = (const float*)d_in[18];
  const float* Wc = (const float*)d_in[19];
  const float* bc = (const float*)d_in[20];
  const int* src0 = (const int*)d_in[21];
  const int* dst0 = (const int*)d_in[22];
  float* out = (float*)d_out;

  char* wsp = (char*)d_ws;
  size_t off = 0;
  auto alloc = [&](size_t bytes)->char*{
    char* p = wsp + off;
    off += (bytes + 255) & ~(size_t)255;
    return p;
  };
  float* bufA = (float*)alloc((size_t)2097152*4);   // x1 / x13
  float* bufB = (float*)alloc((size_t)2097152*4);   // x3
  float* bufC = (float*)alloc((size_t)2097152*4);   // x5 / x11
  float* bufD = (float*)alloc((size_t)2097152*4);   // x7 / x9
  float* bufH = (float*)alloc((size_t)2097152*4);   // pre-norm H
  float* score= (float*)alloc((size_t)M0_*4);
  float* vals2= (float*)alloc((size_t)M1_*4);
  float* vals4= (float*)alloc((size_t)M2_*4);
  float* vals6= (float*)alloc((size_t)M3_*4);
  int* idx2 = (int*)alloc((size_t)M1_*4);   // level2 -> level0
  int* idx4 = (int*)alloc((size_t)M2_*4);   // level4 -> level2
  int* idx6 = (int*)alloc((size_t)M3_*4);   // level6 -> level4
  int* orig4 = (int*)alloc((size_t)M2_*4);  // level4 -> level0
  int* orig6 = (int*)alloc((size_t)M3_*4);  // level6 -> level0
  int* rm02 = (int*)alloc((size_t)M0_*4);
  int* rm04 = (int*)alloc((size_t)M0_*4);
  int* rm06 = (int*)alloc((size_t)M0_*4);
  int* col0 = (int*)alloc((size_t)E_*4);
  int* rowptr0 = (int*)alloc((size_t)(M0_+1)*4);
  int* cursor0 = (int*)alloc((size_t)M0_*4);
  int* degi0 = (int*)alloc((size_t)M0_*4);
  int* bsum  = (int*)alloc((size_t)256*4);
  float* dinv0 = (float*)alloc((size_t)M0_*4);
  float* dinv2 = (float*)alloc((size_t)M1_*4);
  float* dinv4 = (float*)alloc((size_t)M2_*4);
  float* dinv6 = (float*)alloc((size_t)M3_*4);

  auto NB = [](int total){ return (total+255)/256; };

  // ---- level-0 CSR (shared by layers 1 and 7)
  hipMemsetAsync(degi0, 0, (size_t)M0_*4, stream);
  k_deg0<<<NB(E_),256,0,stream>>>(dst0, degi0);
  k_scanA<<<256,256,0,stream>>>(degi0, bsum);
  k_scanB<<<1,256,0,stream>>>(bsum);
  k_scanC<<<256,256,0,stream>>>(degi0, bsum, rowptr0, cursor0, dinv0);
  k_place0<<<NB(E_),256,0,stream>>>(src0, dst0, cursor0, col0);

  // ---- layer 1: gcn(x) -> x1 (bufA) + fused score1
  k_mm<64,32,0><<<dim3(M0_/64,1),256,0,stream>>>(x, W1, bufH, M0_, 128, 32,
      nullptr,nullptr,nullptr,nullptr,nullptr,0);
  k_gather<32,true><<<NB(M0_*8),256,0,stream>>>(rowptr0, col0, dinv0, bufH, b1, bufA, M0_, p1, score);

  // ---- pool 1
  k_topk<<<B_,1024,0,stream>>>(score, 1024, K1_, idx2, vals2);
  hipMemsetAsync(rm02, 0xFF, (size_t)M0_*4, stream);
  k_remap_set<<<NB(M1_),256,0,stream>>>(idx2, rm02, M1_);
  k_deg_orig<<<NB(M1_),256,0,stream>>>(idx2, rowptr0, col0, rm02, dinv2, M1_);

  // ---- layer 2 (X = fused pool of x1) -> x3 (bufB) + fused score2
  k_mm<64,64,1><<<dim3(M1_/64,1),256,0,stream>>>(bufA, W2, bufH, M1_, 32, 64,
      idx2, vals2, nullptr,nullptr,nullptr,0);
  k_gather_rm<64,true><<<NB(M1_*16),256,0,stream>>>(idx2, rowptr0, col0, rm02, dinv2, bufH, b2, bufB, M1_, p2, score);

  // ---- pool 2
  k_topk<<<B_,512,0,stream>>>(score, 512, K2_, idx4, vals4);
  k_compose_idx<<<NB(M2_),256,0,stream>>>(idx2, idx4, orig4, M2_);
  hipMemsetAsync(rm04, 0xFF, (size_t)M0_*4, stream);
  k_remap_set<<<NB(M2_),256,0,stream>>>(orig4, rm04, M2_);
  k_deg_orig<<<NB(M2_),256,0,stream>>>(orig4, rowptr0, col0, rm04, dinv4, M2_);

  // ---- layer 3 -> x5 (bufC) + fused score3
  k_mm<64,64,1><<<dim3(M2_/64,2),256,0,stream>>>(bufB, W3, bufH, M2_, 64, 128,
      idx4, vals4, nullptr,nullptr,nullptr,0);
  k_gather_rm<128,true><<<NB(M2_*32),256,0,stream>>>(orig4, rowptr0, col0, rm04, dinv4, bufH, b3, bufC, M2_, p3, score);

  // ---- pool 3
  k_topk<<<B_,256,0,stream>>>(score, 256, K3_, idx6, vals6);
  k_compose_idx<<<NB(M3_),256,0,stream>>>(orig4, idx6, orig6, M3_);
  hipMemsetAsync(rm06, 0xFF, (size_t)M0_*4, stream);
  k_remap_set<<<NB(M3_),256,0,stream>>>(orig6, rm06, M3_);
  k_deg_orig<<<NB(M3_),256,0,stream>>>(orig6, rowptr0, col0, rm06, dinv6, M3_);

  // ---- layer 4 -> x7 (bufD)
  k_mm<64,64,1><<<dim3(M3_/64,4),256,0,stream>>>(bufC, W4, bufH, M3_, 128, 256,
      idx6, vals6, nullptr,nullptr,nullptr,0);
  k_gather_rm<256,false><<<NB(M3_*64),256,0,stream>>>(orig6, rowptr0, col0, rm06, dinv6, bufH, b4, bufD, M3_, nullptr, nullptr);

  // ---- layer 5 (X = fused concat(x7 scattered, x5)) -> x9 (bufD)
  k_mm<64,64,2><<<dim3(M2_/64,2),256,0,stream>>>(bufC, W5, bufH, M2_, 384, 128,
      nullptr,nullptr, bufD, orig4, rm06, 64);
  k_gather_rm<128,false><<<NB(M2_*32),256,0,stream>>>(orig4, rowptr0, col0, rm04, dinv4, bufH, b5, bufD, M2_, nullptr, nullptr);

  // ---- layer 6 (X = fused concat(x9 scattered, x3)) -> x11 (bufC)
  k_mm<64,64,2><<<dim3(M1_/64,1),256,0,stream>>>(bufB, W6, bufH, M1_, 192, 64,
      nullptr,nullptr, bufD, idx2, rm04, 32);
  k_gather_rm<64,false><<<NB(M1_*16),256,0,stream>>>(idx2, rowptr0, col0, rm02, dinv2, bufH, b6, bufC, M1_, nullptr, nullptr);

  // ---- layer 7 (X = fused concat(x11 scattered, x1)) -> x13 (bufA)
  k_mm<64,32,2><<<dim3(M0_/64,1),256,0,stream>>>(bufA, W7, bufH, M0_, 96, 32,
      nullptr,nullptr, bufC, nullptr, rm02, 16);
  k_gather<32,false><<<NB(M0_*8),256,0,stream>>>(rowptr0, col0, dinv0, bufH, b7, bufA, M0_, nullptr, nullptr);

  // ---- head
  k_head<<<B_,256,0,stream>>>(bufA, Wl, Wc, bc, out);

  (void)in_sizes; (void)n_in; (void)out_size; (void)ws_size;
}